// Round 1
// baseline (280.051 us; speedup 1.0000x reference)
//
#include <hip/hip_runtime.h>
#include <cstdint>
#include <cstddef>
#include <type_traits>

#define DM 1024
#define NHEAD 16
#define DKH 64
#define SEQLEN 2048
#define NBATCH 2
#define MTOT (NBATCH * SEQLEN)  // 4096

typedef __attribute__((ext_vector_type(8))) short bf16x8;
typedef __attribute__((ext_vector_type(4))) float f32x4;

__device__ __forceinline__ uint16_t f2bf(float f) {
  uint32_t x = __float_as_uint(f);
  uint32_t r = x + 0x7FFFu + ((x >> 16) & 1u);  // RNE; inputs finite
  return (uint16_t)(r >> 16);
}

__device__ __forceinline__ void gload_lds16(const void* g, void* l) {
  __builtin_amdgcn_global_load_lds(
      (const __attribute__((address_space(1))) void*)g,
      (__attribute__((address_space(3))) void*)l, 16, 0, 0);
}

__global__ void cvt_f32_bf16_kernel(const float* __restrict__ in,
                                    uint16_t* __restrict__ out, int n4) {
  int i = blockIdx.x * blockDim.x + threadIdx.x;
  if (i >= n4) return;
  float4 v = reinterpret_cast<const float4*>(in)[i];
  uint64_t p = (uint64_t)f2bf(v.x) | ((uint64_t)f2bf(v.y) << 16) |
               ((uint64_t)f2bf(v.z) << 32) | ((uint64_t)f2bf(v.w) << 48);
  reinterpret_cast<uint64_t*>(out)[i] = p;
}

// C[i,j] = sum_k A[i,k]*Bt[j,k] + bias[j].  A: MxK, Bt: NxK, both row-major bf16.
// 128x128 tile, BK=64, 4 waves (2x2 of 64x64), m97 structure.
template <typename OutT>
__global__ __launch_bounds__(256)
void gemm_bt_128(const uint16_t* __restrict__ A, const uint16_t* __restrict__ Bt,
                 const float* __restrict__ bias, OutT* __restrict__ C,
                 int M, int N, int K) {
  __shared__ uint16_t smem[2 * 128 * 64];  // [A 128x64 | Bt 128x64], 32 KiB
  const int tid = threadIdx.x;
  const int wave = tid >> 6, lane = tid & 63;
  const int l15 = lane & 15, l4 = lane >> 4;
  const int brow = blockIdx.x * 128, bcol = blockIdx.y * 128;
  const int wr = (wave >> 1) * 64, wc = (wave & 1) * 64;

  const f32x4 fzero = {0.f, 0.f, 0.f, 0.f};
  f32x4 acc[4][4];
#pragma unroll
  for (int m = 0; m < 4; ++m)
#pragma unroll
    for (int n = 0; n < 4; ++n) acc[m][n] = fzero;

  for (int k0 = 0; k0 < K; k0 += 64) {
    // Stage A-tile (16 KiB) + B-tile (16 KiB): 8 wave-uniform 1 KiB loads/wave.
#pragma unroll
    for (int t = 0; t < 8; ++t) {
      const int o = t * 4096 + wave * 1024 + lane * 16;  // byte offset in smem
      const uint16_t* g;
      if (t < 4) {
        const int row = o >> 7, kk = (o & 127) >> 1;
        g = A + (size_t)(brow + row) * K + (k0 + kk);
      } else {
        const int o2 = o - 16384;
        const int row = o2 >> 7, kk = (o2 & 127) >> 1;
        g = Bt + (size_t)(bcol + row) * K + (k0 + kk);
      }
      gload_lds16(g, (char*)smem + t * 4096 + wave * 1024);
    }
    __syncthreads();
    const uint16_t* At = smem;
    const uint16_t* Bs = smem + 128 * 64;
#pragma unroll
    for (int ks = 0; ks < 2; ++ks) {
      bf16x8 a[4], b[4];
#pragma unroll
      for (int m = 0; m < 4; ++m)
        a[m] = *(const bf16x8*)(At + (wr + m * 16 + l15) * 64 + ks * 32 + l4 * 8);
#pragma unroll
      for (int n = 0; n < 4; ++n)
        b[n] = *(const bf16x8*)(Bs + (wc + n * 16 + l15) * 64 + ks * 32 + l4 * 8);
#pragma unroll
      for (int m = 0; m < 4; ++m)
#pragma unroll
        for (int n = 0; n < 4; ++n)
          acc[m][n] = __builtin_amdgcn_mfma_f32_16x16x32_bf16(a[m], b[n], acc[m][n], 0, 0, 0);
    }
    __syncthreads();
  }

#pragma unroll
  for (int m = 0; m < 4; ++m) {
#pragma unroll
    for (int n = 0; n < 4; ++n) {
      const int gcol = bcol + wc + n * 16 + l15;
      const float bv = bias[gcol];
#pragma unroll
      for (int r = 0; r < 4; ++r) {
        const int grow = brow + wr + m * 16 + l4 * 4 + r;
        const float val = acc[m][n][r] + bv;
        if constexpr (std::is_same<OutT, float>::value)
          C[(size_t)grow * N + gcol] = val;
        else
          C[(size_t)grow * N + gcol] = f2bf(val);
      }
    }
  }
}

// Flash attention fwd: one block = (b, h, 64 q-rows); 4 waves x 16 q-rows.
// Q/K/V laid out [b*S + s][h*64 + d] bf16.
__global__ __launch_bounds__(256)
void attn_fwd_kernel(const uint16_t* __restrict__ Qp, const uint16_t* __restrict__ Kp,
                     const uint16_t* __restrict__ Vp, uint16_t* __restrict__ Op) {
  __shared__ uint16_t Kt[64 * 64];   // [krow][d]
  __shared__ uint16_t Vt[64 * 72];   // [d][krow], stride 72 (16B-aligned rows)
  __shared__ uint16_t Pl[4 * 16 * 64];  // per-wave P re-layout buffer

  const int tid = threadIdx.x;
  const int wave = tid >> 6, lane = tid & 63;
  const int l15 = lane & 15, l4 = lane >> 4;
  const int b = blockIdx.z, h = blockIdx.y;
  const int q0 = blockIdx.x * 64;

  // Q fragments held in registers for the whole K-loop.
  const int qrow = q0 + wave * 16 + l15;
  const uint16_t* qbase = Qp + ((size_t)(b * SEQLEN + qrow)) * DM + h * DKH;
  const bf16x8 qf0 = *(const bf16x8*)(qbase + l4 * 8);
  const bf16x8 qf1 = *(const bf16x8*)(qbase + 32 + l4 * 8);

  const f32x4 fzero = {0.f, 0.f, 0.f, 0.f};
  f32x4 oacc[4];
#pragma unroll
  for (int n = 0; n < 4; ++n) oacc[n] = fzero;
  float mrow[4], lrow[4];
#pragma unroll
  for (int r = 0; r < 4; ++r) { mrow[r] = -1e30f; lrow[r] = 0.f; }

  uint16_t* Pw = Pl + wave * 1024;

  for (int kt = 0; kt < SEQLEN; kt += 64) {
    // Stage K tile (8 KiB) via global_load_lds.
#pragma unroll
    for (int t = 0; t < 2; ++t) {
      const int o = (wave * 2 + t) * 1024 + lane * 16;
      const int row = o >> 7, dd = (o & 127) >> 1;
      const uint16_t* g = Kp + ((size_t)(b * SEQLEN + kt + row)) * DM + h * DKH + dd;
      gload_lds16(g, (char*)Kt + (wave * 2 + t) * 1024);
    }
    // Stage V tile transposed (reg-staged; global_load_lds can't scatter).
    {
      const int krow = tid >> 2, dpart = (tid & 3) * 16;
      const uint16_t* g = Vp + ((size_t)(b * SEQLEN + kt + krow)) * DM + h * DKH + dpart;
      const bf16x8 v0 = *(const bf16x8*)(g);
      const bf16x8 v1 = *(const bf16x8*)(g + 8);
#pragma unroll
      for (int j = 0; j < 8; ++j) Vt[(dpart + j) * 72 + krow] = (uint16_t)v0[j];
#pragma unroll
      for (int j = 0; j < 8; ++j) Vt[(dpart + 8 + j) * 72 + krow] = (uint16_t)v1[j];
    }
    __syncthreads();

    // S = Q K^T  (16x64 per wave). D-layout: qrow=(l4*4+r), kcol=(n*16+l15).
    f32x4 sacc[4];
#pragma unroll
    for (int n = 0; n < 4; ++n) sacc[n] = fzero;
#pragma unroll
    for (int n = 0; n < 4; ++n) {
      const bf16x8 kf0 = *(const bf16x8*)(Kt + (n * 16 + l15) * 64 + l4 * 8);
      const bf16x8 kf1 = *(const bf16x8*)(Kt + (n * 16 + l15) * 64 + 32 + l4 * 8);
      sacc[n] = __builtin_amdgcn_mfma_f32_16x16x32_bf16(qf0, kf0, sacc[n], 0, 0, 0);
      sacc[n] = __builtin_amdgcn_mfma_f32_16x16x32_bf16(qf1, kf1, sacc[n], 0, 0, 0);
    }

    float s[4][4];
#pragma unroll
    for (int n = 0; n < 4; ++n)
#pragma unroll
      for (int r = 0; r < 4; ++r) s[n][r] = sacc[n][r] * 0.125f;  // 1/sqrt(64)

    // Online softmax (row reduce across the 16-lane l15 group).
    float mx[4], mnew[4], scl[4], rs[4];
#pragma unroll
    for (int r = 0; r < 4; ++r) {
      mx[r] = fmaxf(fmaxf(s[0][r], s[1][r]), fmaxf(s[2][r], s[3][r]));
#pragma unroll
      for (int msk = 1; msk < 16; msk <<= 1)
        mx[r] = fmaxf(mx[r], __shfl_xor(mx[r], msk, 64));
      mnew[r] = fmaxf(mrow[r], mx[r]);
      scl[r] = __expf(mrow[r] - mnew[r]);
    }
    float p[4][4];
#pragma unroll
    for (int r = 0; r < 4; ++r) {
      float sum = 0.f;
#pragma unroll
      for (int n = 0; n < 4; ++n) { p[n][r] = __expf(s[n][r] - mnew[r]); sum += p[n][r]; }
      rs[r] = sum;
#pragma unroll
      for (int msk = 1; msk < 16; msk <<= 1)
        rs[r] += __shfl_xor(rs[r], msk, 64);
      lrow[r] = lrow[r] * scl[r] + rs[r];
      mrow[r] = mnew[r];
    }
#pragma unroll
    for (int n = 0; n < 4; ++n)
#pragma unroll
      for (int r = 0; r < 4; ++r) oacc[n][r] *= scl[r];

    // P -> per-wave LDS (re-layout to MFMA A-fragment order). Wave-private: no barrier.
#pragma unroll
    for (int n = 0; n < 4; ++n)
#pragma unroll
      for (int r = 0; r < 4; ++r)
        Pw[(l4 * 4 + r) * 64 + n * 16 + l15] = f2bf(p[n][r]);

    // O += P V.  A-frag: P[l15][k], B-frag: V[k][n*16+l15] = Vt[(n*16+l15)][k].
#pragma unroll
    for (int ks = 0; ks < 2; ++ks) {
      const bf16x8 pf = *(const bf16x8*)(Pw + l15 * 64 + ks * 32 + l4 * 8);
#pragma unroll
      for (int n = 0; n < 4; ++n) {
        const bf16x8 vf = *(const bf16x8*)(Vt + (n * 16 + l15) * 72 + ks * 32 + l4 * 8);
        oacc[n] = __builtin_amdgcn_mfma_f32_16x16x32_bf16(pf, vf, oacc[n], 0, 0, 0);
      }
    }
    __syncthreads();
  }

  // Normalize and store.
#pragma unroll
  for (int n = 0; n < 4; ++n) {
#pragma unroll
    for (int r = 0; r < 4; ++r) {
      const float val = oacc[n][r] / lrow[r];
      const int row = q0 + wave * 16 + l4 * 4 + r;
      Op[((size_t)(b * SEQLEN + row)) * DM + h * DKH + n * 16 + l15] = f2bf(val);
    }
  }
}

extern "C" void kernel_launch(void* const* d_in, const int* in_sizes, int n_in,
                              void* d_out, int out_size, void* d_ws, size_t ws_size,
                              hipStream_t stream) {
  (void)in_sizes; (void)n_in; (void)out_size; (void)ws_size;
  const float* query = (const float*)d_in[0];
  const float* key_i = (const float*)d_in[1];
  const float* value = (const float*)d_in[2];
  const float* Wq = (const float*)d_in[3];
  const float* bq = (const float*)d_in[4];
  const float* Wk = (const float*)d_in[5];
  const float* bk = (const float*)d_in[6];
  const float* Wv = (const float*)d_in[7];
  const float* bv = (const float*)d_in[8];
  const float* Wo = (const float*)d_in[9];
  const float* bo = (const float*)d_in[10];
  float* out = (float*)d_out;

  char* ws = (char*)d_ws;
  const size_t MB = 1ull << 20;
  uint16_t* xq  = (uint16_t*)(ws + 0 * MB);    // 8 MB each (4096x1024 bf16)
  uint16_t* xk  = (uint16_t*)(ws + 8 * MB);
  uint16_t* xv  = (uint16_t*)(ws + 16 * MB);
  uint16_t* wqb = (uint16_t*)(ws + 24 * MB);   // 2 MB each (1024x1024 bf16)
  uint16_t* wkb = (uint16_t*)(ws + 26 * MB);
  uint16_t* wvb = (uint16_t*)(ws + 28 * MB);
  uint16_t* wob = (uint16_t*)(ws + 30 * MB);
  uint16_t* Qp  = (uint16_t*)(ws + 32 * MB);
  uint16_t* Kp  = (uint16_t*)(ws + 40 * MB);
  uint16_t* Vp  = (uint16_t*)(ws + 48 * MB);
  uint16_t* AO  = (uint16_t*)(ws + 56 * MB);   // ends at 64 MB

  const int n4x = (MTOT * DM) / 4;  // 1 Mi float4s
  const int n4w = (DM * DM) / 4;    // 256 Ki float4s
  const int blk = 256;
  cvt_f32_bf16_kernel<<<(n4x + blk - 1) / blk, blk, 0, stream>>>(query, xq, n4x);
  cvt_f32_bf16_kernel<<<(n4x + blk - 1) / blk, blk, 0, stream>>>(key_i, xk, n4x);
  cvt_f32_bf16_kernel<<<(n4x + blk - 1) / blk, blk, 0, stream>>>(value, xv, n4x);
  cvt_f32_bf16_kernel<<<(n4w + blk - 1) / blk, blk, 0, stream>>>(Wq, wqb, n4w);
  cvt_f32_bf16_kernel<<<(n4w + blk - 1) / blk, blk, 0, stream>>>(Wk, wkb, n4w);
  cvt_f32_bf16_kernel<<<(n4w + blk - 1) / blk, blk, 0, stream>>>(Wv, wvb, n4w);
  cvt_f32_bf16_kernel<<<(n4w + blk - 1) / blk, blk, 0, stream>>>(Wo, wob, n4w);

  dim3 gg(MTOT / 128, DM / 128);  // 32 x 8
  gemm_bt_128<uint16_t><<<gg, 256, 0, stream>>>(xq, wqb, bq, Qp, MTOT, DM, DM);
  gemm_bt_128<uint16_t><<<gg, 256, 0, stream>>>(xk, wkb, bk, Kp, MTOT, DM, DM);
  gemm_bt_128<uint16_t><<<gg, 256, 0, stream>>>(xv, wvb, bv, Vp, MTOT, DM, DM);

  dim3 ga(SEQLEN / 64, NHEAD, NBATCH);  // 32 x 16 x 2
  attn_fwd_kernel<<<ga, 256, 0, stream>>>(Qp, Kp, Vp, AO);

  gemm_bt_128<float><<<gg, 256, 0, stream>>>(AO, wob, bo, out, MTOT, DM, DM);
}

// Round 2
// 249.574 us; speedup vs baseline: 1.1221x; 1.1221x over previous
//
#include <hip/hip_runtime.h>
#include <cstdint>
#include <cstddef>
#include <type_traits>

#define DM 1024
#define NHEAD 16
#define DKH 64
#define SEQLEN 2048
#define NBATCH 2
#define MTOT (NBATCH * SEQLEN)  // 4096

typedef __attribute__((ext_vector_type(8))) short bf16x8;
typedef __attribute__((ext_vector_type(4))) float f32x4;

__device__ __forceinline__ uint16_t f2bf(float f) {
  uint32_t x = __float_as_uint(f);
  uint32_t r = x + 0x7FFFu + ((x >> 16) & 1u);  // RNE; inputs finite
  return (uint16_t)(r >> 16);
}

__device__ __forceinline__ void gload_lds16(const void* g, void* l) {
  __builtin_amdgcn_global_load_lds(
      (const __attribute__((address_space(1))) void*)g,
      (__attribute__((address_space(3))) void*)l, 16, 0, 0);
}

// ---- fused fp32 -> bf16 convert over 7 regions in one launch ----
struct CvtArgs {
  const float* src[7];
  uint16_t* dst[7];
  int end4[7];  // cumulative float4 counts
};

__global__ void cvt_all_kernel(CvtArgs a) {
  int i = blockIdx.x * blockDim.x + threadIdx.x;
  int r = 0;
#pragma unroll
  for (int j = 0; j < 7; ++j)
    if (i >= a.end4[j]) r = j + 1;
  if (r >= 7) return;
  int local = i - (r == 0 ? 0 : a.end4[r - 1]);
  float4 v = reinterpret_cast<const float4*>(a.src[r])[local];
  uint64_t p = (uint64_t)f2bf(v.x) | ((uint64_t)f2bf(v.y) << 16) |
               ((uint64_t)f2bf(v.z) << 32) | ((uint64_t)f2bf(v.w) << 48);
  reinterpret_cast<uint64_t*>(a.dst[r])[local] = p;
}

// C[i,j] = sum_k A[i,k]*Bt[j,k] + bias[j].  A: MxK, Bt: NxK, both row-major bf16.
// 128x128 tile, BK=64, 4 waves (2x2 of 64x64), m97 structure.
template <typename OutT>
__global__ __launch_bounds__(256)
void gemm_bt_128(const uint16_t* __restrict__ A, const uint16_t* __restrict__ Bt,
                 const float* __restrict__ bias, OutT* __restrict__ C,
                 int M, int N, int K) {
  __shared__ uint16_t smem[2 * 128 * 64];  // [A 128x64 | Bt 128x64], 32 KiB
  const int tid = threadIdx.x;
  const int wave = tid >> 6, lane = tid & 63;
  const int l15 = lane & 15, l4 = lane >> 4;
  const int brow = blockIdx.x * 128, bcol = blockIdx.y * 128;
  const int wr = (wave >> 1) * 64, wc = (wave & 1) * 64;

  const f32x4 fzero = {0.f, 0.f, 0.f, 0.f};
  f32x4 acc[4][4];
#pragma unroll
  for (int m = 0; m < 4; ++m)
#pragma unroll
    for (int n = 0; n < 4; ++n) acc[m][n] = fzero;

  for (int k0 = 0; k0 < K; k0 += 64) {
#pragma unroll
    for (int t = 0; t < 8; ++t) {
      const int o = t * 4096 + wave * 1024 + lane * 16;  // byte offset in smem
      const uint16_t* g;
      if (t < 4) {
        const int row = o >> 7, kk = (o & 127) >> 1;
        g = A + (size_t)(brow + row) * K + (k0 + kk);
      } else {
        const int o2 = o - 16384;
        const int row = o2 >> 7, kk = (o2 & 127) >> 1;
        g = Bt + (size_t)(bcol + row) * K + (k0 + kk);
      }
      gload_lds16(g, (char*)smem + t * 4096 + wave * 1024);
    }
    __syncthreads();
    const uint16_t* At = smem;
    const uint16_t* Bs = smem + 128 * 64;
#pragma unroll
    for (int ks = 0; ks < 2; ++ks) {
      bf16x8 a[4], b[4];
#pragma unroll
      for (int m = 0; m < 4; ++m)
        a[m] = *(const bf16x8*)(At + (wr + m * 16 + l15) * 64 + ks * 32 + l4 * 8);
#pragma unroll
      for (int n = 0; n < 4; ++n)
        b[n] = *(const bf16x8*)(Bs + (wc + n * 16 + l15) * 64 + ks * 32 + l4 * 8);
#pragma unroll
      for (int m = 0; m < 4; ++m)
#pragma unroll
        for (int n = 0; n < 4; ++n)
          acc[m][n] = __builtin_amdgcn_mfma_f32_16x16x32_bf16(a[m], b[n], acc[m][n], 0, 0, 0);
    }
    __syncthreads();
  }

#pragma unroll
  for (int m = 0; m < 4; ++m) {
#pragma unroll
    for (int n = 0; n < 4; ++n) {
      const int gcol = bcol + wc + n * 16 + l15;
      const float bv = bias[gcol];
#pragma unroll
      for (int r = 0; r < 4; ++r) {
        const int grow = brow + wr + m * 16 + l4 * 4 + r;
        const float val = acc[m][n][r] + bv;
        if constexpr (std::is_same<OutT, float>::value)
          C[(size_t)grow * N + gcol] = val;
        else
          C[(size_t)grow * N + gcol] = f2bf(val);
      }
    }
  }
}

// Flash attention fwd: one block = (b, h, 64 q-rows); 4 waves x 16 q-rows.
// All LDS tiles XOR-swizzled to kill the stride-128B bank conflicts:
//   Kt: elem(row,d) at byte row*128 + (2d ^ fK(row)),   fK(r) = (r&7)<<4
//   Vt: elem(d,k)   at byte d*128  + (2k ^ fV(d)),      fV(d) = ((d+(d>>3))&7)<<4
//   Pl: elem(q,k)   at byte q*128  + (2k ^ fP(q)),      fP(q) = (q&7)<<4
// Kt is staged by global_load_lds with a PRE-SWIZZLED SOURCE address
// (LDS dest stays linear; m173 pattern).
__global__ __launch_bounds__(256)
void attn_fwd_kernel(const uint16_t* __restrict__ Qp, const uint16_t* __restrict__ Kp,
                     const uint16_t* __restrict__ Vp, uint16_t* __restrict__ Op) {
  __shared__ uint16_t Kt[64 * 64];
  __shared__ uint16_t Vt[64 * 64];
  __shared__ uint16_t Pl[4 * 16 * 64];

  const int tid = threadIdx.x;
  const int wave = tid >> 6, lane = tid & 63;
  const int l15 = lane & 15, l4 = lane >> 4;
  const int bb = blockIdx.z, h = blockIdx.y;
  const int q0 = blockIdx.x * 64;

  // Q fragments held in registers for the whole K-loop.
  const int qrow = q0 + wave * 16 + l15;
  const uint16_t* qbase = Qp + ((size_t)(bb * SEQLEN + qrow)) * DM + h * DKH;
  const bf16x8 qf0 = *(const bf16x8*)(qbase + l4 * 8);
  const bf16x8 qf1 = *(const bf16x8*)(qbase + 32 + l4 * 8);

  const f32x4 fzero = {0.f, 0.f, 0.f, 0.f};
  f32x4 oacc[4];
#pragma unroll
  for (int n = 0; n < 4; ++n) oacc[n] = fzero;
  float mrow[4], lrow[4];
#pragma unroll
  for (int r = 0; r < 4; ++r) { mrow[r] = -1e30f; lrow[r] = 0.f; }

  char* Pw = (char*)(Pl + wave * 1024);

  for (int kt = 0; kt < SEQLEN; kt += 64) {
    // Stage K tile via global_load_lds, source pre-swizzled.
#pragma unroll
    for (int t = 0; t < 2; ++t) {
      const int chunk = (wave * 2 + t) * 1024;
      const int o = chunk + lane * 16;
      const int row = o >> 7;           // k-row within tile
      const int bir = o & 127;          // byte-in-row (16B aligned)
      const int dsrc = (bir ^ ((row & 7) << 4)) >> 1;
      const uint16_t* g = Kp + ((size_t)(bb * SEQLEN + kt + row)) * DM + h * DKH + dsrc;
      gload_lds16(g, (char*)Kt + chunk);
    }
    // Stage V tile transposed + swizzled (reg-staged).
    {
      const int krow = tid >> 2, dpart = (tid & 3) * 16;
      const uint16_t* g = Vp + ((size_t)(bb * SEQLEN + kt + krow)) * DM + h * DKH + dpart;
      const bf16x8 v0 = *(const bf16x8*)(g);
      const bf16x8 v1 = *(const bf16x8*)(g + 8);
#pragma unroll
      for (int j = 0; j < 8; ++j) {
        const int d = dpart + j;
        const int fv = ((d + (d >> 3)) & 7) << 4;
        *(uint16_t*)((char*)Vt + d * 128 + ((krow * 2) ^ fv)) = (uint16_t)v0[j];
      }
#pragma unroll
      for (int j = 0; j < 8; ++j) {
        const int d = dpart + 8 + j;
        const int fv = ((d + (d >> 3)) & 7) << 4;
        *(uint16_t*)((char*)Vt + d * 128 + ((krow * 2) ^ fv)) = (uint16_t)v1[j];
      }
    }
    __syncthreads();

    // S = Q K^T  (16x64 per wave). D-layout: qrow=(l4*4+r), kcol=(n*16+l15).
    f32x4 sacc[4];
#pragma unroll
    for (int n = 0; n < 4; ++n) sacc[n] = fzero;
#pragma unroll
    for (int n = 0; n < 4; ++n) {
      const int krow = n * 16 + l15;
      const char* kr = (const char*)Kt + krow * 128;
      const int fk = (krow & 7) << 4;
      const bf16x8 kf0 = *(const bf16x8*)(kr + ((l4 * 16) ^ fk));
      const bf16x8 kf1 = *(const bf16x8*)(kr + ((64 + l4 * 16) ^ fk));
      sacc[n] = __builtin_amdgcn_mfma_f32_16x16x32_bf16(qf0, kf0, sacc[n], 0, 0, 0);
      sacc[n] = __builtin_amdgcn_mfma_f32_16x16x32_bf16(qf1, kf1, sacc[n], 0, 0, 0);
    }

    float s[4][4];
#pragma unroll
    for (int n = 0; n < 4; ++n)
#pragma unroll
      for (int r = 0; r < 4; ++r) s[n][r] = sacc[n][r] * 0.125f;  // 1/sqrt(64)

    // Online softmax (row reduce across the 16-lane l15 group).
    float mx[4], mnew[4], scl[4], rs[4];
#pragma unroll
    for (int r = 0; r < 4; ++r) {
      mx[r] = fmaxf(fmaxf(s[0][r], s[1][r]), fmaxf(s[2][r], s[3][r]));
#pragma unroll
      for (int msk = 1; msk < 16; msk <<= 1)
        mx[r] = fmaxf(mx[r], __shfl_xor(mx[r], msk, 64));
      mnew[r] = fmaxf(mrow[r], mx[r]);
      scl[r] = __expf(mrow[r] - mnew[r]);
    }
    float p[4][4];
#pragma unroll
    for (int r = 0; r < 4; ++r) {
      float sum = 0.f;
#pragma unroll
      for (int n = 0; n < 4; ++n) { p[n][r] = __expf(s[n][r] - mnew[r]); sum += p[n][r]; }
      rs[r] = sum;
#pragma unroll
      for (int msk = 1; msk < 16; msk <<= 1)
        rs[r] += __shfl_xor(rs[r], msk, 64);
      lrow[r] = lrow[r] * scl[r] + rs[r];
      mrow[r] = mnew[r];
    }
#pragma unroll
    for (int n = 0; n < 4; ++n)
#pragma unroll
      for (int r = 0; r < 4; ++r) oacc[n][r] *= scl[r];

    // P -> per-wave LDS (swizzled). Wave-private: no barrier needed.
#pragma unroll
    for (int n = 0; n < 4; ++n)
#pragma unroll
      for (int r = 0; r < 4; ++r) {
        const int qr = l4 * 4 + r;
        const int fp = (qr & 7) << 4;
        *(uint16_t*)(Pw + qr * 128 + (((n * 32 + l15 * 2)) ^ fp)) = f2bf(p[n][r]);
      }

    // O += P V.  A-frag: P[l15][k], B-frag: V[k][col] = Vt[(col)][k].
#pragma unroll
    for (int ks = 0; ks < 2; ++ks) {
      const int fp = (l15 & 7) << 4;
      const bf16x8 pf = *(const bf16x8*)(Pw + l15 * 128 + ((ks * 64 + l4 * 16) ^ fp));
#pragma unroll
      for (int n = 0; n < 4; ++n) {
        const int vrow = n * 16 + l15;
        const int fv = ((vrow + (vrow >> 3)) & 7) << 4;
        const bf16x8 vf = *(const bf16x8*)((const char*)Vt + vrow * 128 +
                                           ((ks * 64 + l4 * 16) ^ fv));
        oacc[n] = __builtin_amdgcn_mfma_f32_16x16x32_bf16(pf, vf, oacc[n], 0, 0, 0);
      }
    }
    __syncthreads();
  }

  // Normalize and store.
  float il[4];
#pragma unroll
  for (int r = 0; r < 4; ++r) il[r] = 1.0f / lrow[r];
#pragma unroll
  for (int n = 0; n < 4; ++n) {
#pragma unroll
    for (int r = 0; r < 4; ++r) {
      const float val = oacc[n][r] * il[r];
      const int row = q0 + wave * 16 + l4 * 4 + r;
      Op[((size_t)(bb * SEQLEN + row)) * DM + h * DKH + n * 16 + l15] = f2bf(val);
    }
  }
}

extern "C" void kernel_launch(void* const* d_in, const int* in_sizes, int n_in,
                              void* d_out, int out_size, void* d_ws, size_t ws_size,
                              hipStream_t stream) {
  (void)in_sizes; (void)n_in; (void)out_size; (void)ws_size;
  const float* query = (const float*)d_in[0];
  const float* key_i = (const float*)d_in[1];
  const float* value = (const float*)d_in[2];
  const float* Wq = (const float*)d_in[3];
  const float* bq = (const float*)d_in[4];
  const float* Wk = (const float*)d_in[5];
  const float* bk = (const float*)d_in[6];
  const float* Wv = (const float*)d_in[7];
  const float* bv = (const float*)d_in[8];
  const float* Wo = (const float*)d_in[9];
  const float* bo = (const float*)d_in[10];
  float* out = (float*)d_out;

  char* ws = (char*)d_ws;
  const size_t MB = 1ull << 20;
  uint16_t* xq  = (uint16_t*)(ws + 0 * MB);    // 8 MB each (4096x1024 bf16)
  uint16_t* xk  = (uint16_t*)(ws + 8 * MB);
  uint16_t* xv  = (uint16_t*)(ws + 16 * MB);
  uint16_t* wqb = (uint16_t*)(ws + 24 * MB);   // 2 MB each (1024x1024 bf16)
  uint16_t* wkb = (uint16_t*)(ws + 26 * MB);
  uint16_t* wvb = (uint16_t*)(ws + 28 * MB);
  uint16_t* wob = (uint16_t*)(ws + 30 * MB);
  uint16_t* Qp  = (uint16_t*)(ws + 32 * MB);
  uint16_t* Kp  = (uint16_t*)(ws + 40 * MB);
  uint16_t* Vp  = (uint16_t*)(ws + 48 * MB);
  uint16_t* AO  = (uint16_t*)(ws + 56 * MB);   // ends at 64 MB

  const int n4x = (MTOT * DM) / 4;  // 1 Mi float4s per x
  const int n4w = (DM * DM) / 4;    // 256 Ki float4s per weight
  CvtArgs ca;
  ca.src[0] = query; ca.dst[0] = xq;
  ca.src[1] = key_i; ca.dst[1] = xk;
  ca.src[2] = value; ca.dst[2] = xv;
  ca.src[3] = Wq;    ca.dst[3] = wqb;
  ca.src[4] = Wk;    ca.dst[4] = wkb;
  ca.src[5] = Wv;    ca.dst[5] = wvb;
  ca.src[6] = Wo;    ca.dst[6] = wob;
  int acc = 0;
  for (int j = 0; j < 7; ++j) { acc += (j < 3) ? n4x : n4w; ca.end4[j] = acc; }
  const int blk = 256;
  cvt_all_kernel<<<(acc + blk - 1) / blk, blk, 0, stream>>>(ca);

  dim3 gg(MTOT / 128, DM / 128);  // 32 x 8
  gemm_bt_128<uint16_t><<<gg, 256, 0, stream>>>(xq, wqb, bq, Qp, MTOT, DM, DM);
  gemm_bt_128<uint16_t><<<gg, 256, 0, stream>>>(xk, wkb, bk, Kp, MTOT, DM, DM);
  gemm_bt_128<uint16_t><<<gg, 256, 0, stream>>>(xv, wvb, bv, Vp, MTOT, DM, DM);

  dim3 ga(SEQLEN / 64, NHEAD, NBATCH);  // 32 x 16 x 2
  attn_fwd_kernel<<<ga, 256, 0, stream>>>(Qp, Kp, Vp, AO);

  gemm_bt_128<float><<<gg, 256, 0, stream>>>(AO, wob, bo, out, MTOT, DM, DM);
}

// Round 3
// 197.994 us; speedup vs baseline: 1.4144x; 1.2605x over previous
//
#include <hip/hip_runtime.h>
#include <cstdint>
#include <cstddef>
#include <type_traits>

#define DM 1024
#define NHEAD 16
#define DKH 64
#define SEQLEN 2048
#define NBATCH 2
#define MTOT (NBATCH * SEQLEN)  // 4096

typedef __attribute__((ext_vector_type(8))) short bf16x8;
typedef __attribute__((ext_vector_type(4))) float f32x4;

// (1/sqrt(Dk)) * log2(e): folded into Q projection; attn softmax uses exp2.
#define QSCALE 0.18033688011112042f

__device__ __forceinline__ uint16_t f2bf(float f) {
  uint32_t x = __float_as_uint(f);
  uint32_t r = x + 0x7FFFu + ((x >> 16) & 1u);  // RNE; inputs finite
  return (uint16_t)(r >> 16);
}

__device__ __forceinline__ void gload_lds16(const void* g, void* l) {
  __builtin_amdgcn_global_load_lds(
      (const __attribute__((address_space(1))) void*)g,
      (__attribute__((address_space(3))) void*)l, 16, 0, 0);
}

// ---- fused fp32 -> bf16 convert over 7 regions in one launch ----
struct CvtArgs {
  const float* src[7];
  uint16_t* dst[7];
  int end4[7];  // cumulative float4 counts
};

__global__ void cvt_all_kernel(CvtArgs a) {
  int i = blockIdx.x * blockDim.x + threadIdx.x;
  int r = 0;
#pragma unroll
  for (int j = 0; j < 7; ++j)
    if (i >= a.end4[j]) r = j + 1;
  if (r >= 7) return;
  int local = i - (r == 0 ? 0 : a.end4[r - 1]);
  float4 v = reinterpret_cast<const float4*>(a.src[r])[local];
  uint64_t p = (uint64_t)f2bf(v.x) | ((uint64_t)f2bf(v.y) << 16) |
               ((uint64_t)f2bf(v.z) << 32) | ((uint64_t)f2bf(v.w) << 48);
  reinterpret_cast<uint64_t*>(a.dst[r])[local] = p;
}

// C[i,j] = sum_k A[i,k]*Bt[j,k] + bias[j].  A: MxK, Bt: NxK, row-major bf16.
// 128x128 tile, BK=64, 4 waves (2x2 of 64x64), m97 structure.
// MODE 0: bf16 out.  MODE 1: bf16 out scaled by QSCALE (Q projection).
// MODE 2: bf16 out TRANSPOSED to [b, h, d, s] (V projection -> V^T for attn).
// MODE 3: f32 out (final projection).
template <int MODE>
__global__ __launch_bounds__(256)
void gemm_bt_128(const uint16_t* __restrict__ A, const uint16_t* __restrict__ Bt,
                 const float* __restrict__ bias, void* __restrict__ Cv,
                 int M, int N, int K) {
  __shared__ uint16_t smem[2 * 128 * 64];  // 32 KiB
  const int tid = threadIdx.x;
  const int wave = tid >> 6, lane = tid & 63;
  const int l15 = lane & 15, l4 = lane >> 4;
  const int brow = blockIdx.x * 128, bcol = blockIdx.y * 128;
  const int wr = (wave >> 1) * 64, wc = (wave & 1) * 64;

  const f32x4 fzero = {0.f, 0.f, 0.f, 0.f};
  f32x4 acc[4][4];
#pragma unroll
  for (int m = 0; m < 4; ++m)
#pragma unroll
    for (int n = 0; n < 4; ++n) acc[m][n] = fzero;

  for (int k0 = 0; k0 < K; k0 += 64) {
#pragma unroll
    for (int t = 0; t < 8; ++t) {
      const int o = t * 4096 + wave * 1024 + lane * 16;  // byte offset in smem
      const uint16_t* g;
      if (t < 4) {
        const int row = o >> 7, kk = (o & 127) >> 1;
        g = A + (size_t)(brow + row) * K + (k0 + kk);
      } else {
        const int o2 = o - 16384;
        const int row = o2 >> 7, kk = (o2 & 127) >> 1;
        g = Bt + (size_t)(bcol + row) * K + (k0 + kk);
      }
      gload_lds16(g, (char*)smem + t * 4096 + wave * 1024);
    }
    __syncthreads();
    const uint16_t* At = smem;
    const uint16_t* Bs = smem + 128 * 64;
#pragma unroll
    for (int ks = 0; ks < 2; ++ks) {
      bf16x8 a[4], b[4];
#pragma unroll
      for (int m = 0; m < 4; ++m)
        a[m] = *(const bf16x8*)(At + (wr + m * 16 + l15) * 64 + ks * 32 + l4 * 8);
#pragma unroll
      for (int n = 0; n < 4; ++n)
        b[n] = *(const bf16x8*)(Bs + (wc + n * 16 + l15) * 64 + ks * 32 + l4 * 8);
#pragma unroll
      for (int m = 0; m < 4; ++m)
#pragma unroll
        for (int n = 0; n < 4; ++n)
          acc[m][n] = __builtin_amdgcn_mfma_f32_16x16x32_bf16(a[m], b[n], acc[m][n], 0, 0, 0);
    }
    __syncthreads();
  }

#pragma unroll
  for (int m = 0; m < 4; ++m) {
#pragma unroll
    for (int n = 0; n < 4; ++n) {
      const int gcol = bcol + wc + n * 16 + l15;
      const float bv = bias[gcol];
      if constexpr (MODE == 2) {
        // V^T output: element (s=grow, col=gcol) -> VT[(b*NHEAD+h)*DKH + d][s].
        const int grow0 = brow + wr + m * 16 + l4 * 4;
        const int b_ = grow0 >> 11, s_ = grow0 & 2047;
        const int h_ = gcol >> 6, d_ = gcol & 63;
        uint16_t* dst = (uint16_t*)Cv +
            ((size_t)((b_ * NHEAD + h_) * DKH + d_)) * SEQLEN + s_;
        uint64_t pk = (uint64_t)f2bf(acc[m][n][0] + bv) |
                      ((uint64_t)f2bf(acc[m][n][1] + bv) << 16) |
                      ((uint64_t)f2bf(acc[m][n][2] + bv) << 32) |
                      ((uint64_t)f2bf(acc[m][n][3] + bv) << 48);
        *(uint64_t*)dst = pk;  // 4 consecutive s, 8B aligned
      } else {
#pragma unroll
        for (int r = 0; r < 4; ++r) {
          const int grow = brow + wr + m * 16 + l4 * 4 + r;
          float val = acc[m][n][r] + bv;
          if constexpr (MODE == 1) val *= QSCALE;
          if constexpr (MODE == 3)
            ((float*)Cv)[(size_t)grow * N + gcol] = val;
          else
            ((uint16_t*)Cv)[(size_t)grow * N + gcol] = f2bf(val);
        }
      }
    }
  }
}

// Flash attention fwd, swapped-QK^T structure.
// One block = (b, h, 64 q-rows); 4 waves x 16 q-rows.
// Q pre-scaled by (1/8)*log2e in the Q-GEMM -> softmax uses exp2.
// K staged [k][d], V^T staged [d][k], both via global_load_lds with
// pre-swizzled SOURCE (XOR (row&7)<<4 on the 16B slot; LDS dest linear).
// mfma(K,Q) puts S^T in accumulators: lane (l15,l4) holds
// S[q=wave*16+l15][k=n*16+l4*4+r] -> softmax state is per-lane scalar
// (uniform across l4 after 2 shfl_xor reduces).
__global__ __launch_bounds__(256)
void attn_fwd_kernel(const uint16_t* __restrict__ Qp, const uint16_t* __restrict__ Kp,
                     const uint16_t* __restrict__ VTp, uint16_t* __restrict__ Op) {
  __shared__ uint16_t Kt[64 * 64];
  __shared__ uint16_t Vt[64 * 64];
  __shared__ uint16_t Pl[4 * 16 * 64];

  const int tid = threadIdx.x;
  const int wave = tid >> 6, lane = tid & 63;
  const int l15 = lane & 15, l4 = lane >> 4;
  const int bb = blockIdx.z, h = blockIdx.y;
  const int q0 = blockIdx.x * 64;

  // Q fragments (pre-scaled) held in registers for the whole K-loop.
  const int qrow = q0 + wave * 16 + l15;
  const uint16_t* qbase = Qp + ((size_t)(bb * SEQLEN + qrow)) * DM + h * DKH;
  const bf16x8 qf0 = *(const bf16x8*)(qbase + l4 * 8);
  const bf16x8 qf1 = *(const bf16x8*)(qbase + 32 + l4 * 8);

  const f32x4 fzero = {0.f, 0.f, 0.f, 0.f};
  f32x4 oacc[4];
#pragma unroll
  for (int n = 0; n < 4; ++n) oacc[n] = fzero;
  float mrow = -1e30f, lrow = 0.f;  // per-lane q = wave*16+l15 (dup across l4)

  char* Pw = (char*)(Pl + wave * 1024);
  const int fP = (l15 & 7) << 4;
  const uint16_t* VTbase = VTp + ((size_t)((bb * NHEAD + h) * DKH)) * SEQLEN;

  for (int kt = 0; kt < SEQLEN; kt += 64) {
    // Stage K [k][d] and V^T [d][k] tiles, sources pre-swizzled.
#pragma unroll
    for (int t = 0; t < 2; ++t) {
      const int chunk = (wave * 2 + t) * 1024;
      const int o = chunk + lane * 16;
      const int row = o >> 7;
      const int esw = ((o & 127) ^ ((row & 7) << 4)) >> 1;  // swizzled elem-in-row
      const uint16_t* gK = Kp + ((size_t)(bb * SEQLEN + kt + row)) * DM + h * DKH + esw;
      gload_lds16(gK, (char*)Kt + chunk);
      const uint16_t* gV = VTbase + (size_t)row * SEQLEN + kt + esw;
      gload_lds16(gV, (char*)Vt + chunk);
    }
    __syncthreads();

    // S^T = K Q^T  (swapped operands).
    f32x4 sacc[4];
#pragma unroll
    for (int n = 0; n < 4; ++n) sacc[n] = fzero;
    __builtin_amdgcn_s_setprio(1);
#pragma unroll
    for (int n = 0; n < 4; ++n) {
      const int krow = n * 16 + l15;
      const char* kr = (const char*)Kt + krow * 128;
      const int fk = (krow & 7) << 4;
      const bf16x8 kf0 = *(const bf16x8*)(kr + ((l4 * 16) ^ fk));
      const bf16x8 kf1 = *(const bf16x8*)(kr + ((64 + l4 * 16) ^ fk));
      sacc[n] = __builtin_amdgcn_mfma_f32_16x16x32_bf16(kf0, qf0, sacc[n], 0, 0, 0);
      sacc[n] = __builtin_amdgcn_mfma_f32_16x16x32_bf16(kf1, qf1, sacc[n], 0, 0, 0);
    }
    __builtin_amdgcn_s_setprio(0);

    // Softmax (log2 domain). Lane's 16 values cover k = n*16 + l4*4 + r.
    float mx = sacc[0][0];
#pragma unroll
    for (int n = 0; n < 4; ++n)
#pragma unroll
      for (int r = 0; r < 4; ++r) mx = fmaxf(mx, sacc[n][r]);
    mx = fmaxf(mx, __shfl_xor(mx, 16, 64));
    mx = fmaxf(mx, __shfl_xor(mx, 32, 64));

    float mnew = mrow, scl = 1.f;
    if (__any(mx > mrow + 8.f)) {  // defer-max, THR=8 (log2 domain: P <= 256)
      mnew = fmaxf(mrow, mx);
      scl = exp2f(mrow - mnew);
      const float s0 = __shfl(scl, l4 * 4 + 0, 64);
      const float s1 = __shfl(scl, l4 * 4 + 1, 64);
      const float s2 = __shfl(scl, l4 * 4 + 2, 64);
      const float s3 = __shfl(scl, l4 * 4 + 3, 64);
#pragma unroll
      for (int n = 0; n < 4; ++n) {
        oacc[n][0] *= s0; oacc[n][1] *= s1; oacc[n][2] *= s2; oacc[n][3] *= s3;
      }
    }

    float p[4][4];
    float sum = 0.f;
#pragma unroll
    for (int n = 0; n < 4; ++n)
#pragma unroll
      for (int r = 0; r < 4; ++r) {
        p[n][r] = exp2f(sacc[n][r] - mnew);
        sum += p[n][r];
      }
    sum += __shfl_xor(sum, 16, 64);
    sum += __shfl_xor(sum, 32, 64);
    lrow = lrow * scl + sum;
    mrow = mnew;

    // P -> Pl row q=l15, element k=n*16+l4*4+r at byte 2k (^ swizzle).
    // 8 packed ds_write_b32 per thread; wave-private, no barrier.
#pragma unroll
    for (int n = 0; n < 4; ++n) {
      const uint32_t w01 = (uint32_t)f2bf(p[n][0]) | ((uint32_t)f2bf(p[n][1]) << 16);
      const uint32_t w23 = (uint32_t)f2bf(p[n][2]) | ((uint32_t)f2bf(p[n][3]) << 16);
      const int base = n * 32 + l4 * 8;
      *(uint32_t*)(Pw + l15 * 128 + (base ^ fP)) = w01;
      *(uint32_t*)(Pw + l15 * 128 + ((base + 4) ^ fP)) = w23;
    }

    // O += P V.  A-frag: P[q=l15][k], B-frag: V^T[d=n*16+l15][k].
    __builtin_amdgcn_s_setprio(1);
#pragma unroll
    for (int ks = 0; ks < 2; ++ks) {
      const bf16x8 pf = *(const bf16x8*)(Pw + l15 * 128 + ((ks * 64 + l4 * 16) ^ fP));
#pragma unroll
      for (int n = 0; n < 4; ++n) {
        const int vrow = n * 16 + l15;
        const int fv = (vrow & 7) << 4;
        const bf16x8 vf = *(const bf16x8*)((const char*)Vt + vrow * 128 +
                                           ((ks * 64 + l4 * 16) ^ fv));
        oacc[n] = __builtin_amdgcn_mfma_f32_16x16x32_bf16(pf, vf, oacc[n], 0, 0, 0);
      }
    }
    __builtin_amdgcn_s_setprio(0);
    __syncthreads();
  }

  // Normalize and store. oacc: O[q=wave*16+l4*4+r][d=n*16+l15].
  const float il = 1.0f / lrow;
  const float i0 = __shfl(il, l4 * 4 + 0, 64);
  const float i1 = __shfl(il, l4 * 4 + 1, 64);
  const float i2 = __shfl(il, l4 * 4 + 2, 64);
  const float i3 = __shfl(il, l4 * 4 + 3, 64);
#pragma unroll
  for (int n = 0; n < 4; ++n) {
    const int col = h * DKH + n * 16 + l15;
    const int row0 = q0 + wave * 16 + l4 * 4;
    uint16_t* ob = Op + ((size_t)(bb * SEQLEN + row0)) * DM + col;
    ob[0 * DM] = f2bf(oacc[n][0] * i0);
    ob[1 * DM] = f2bf(oacc[n][1] * i1);
    ob[2 * DM] = f2bf(oacc[n][2] * i2);
    ob[3 * DM] = f2bf(oacc[n][3] * i3);
  }
}

extern "C" void kernel_launch(void* const* d_in, const int* in_sizes, int n_in,
                              void* d_out, int out_size, void* d_ws, size_t ws_size,
                              hipStream_t stream) {
  (void)in_sizes; (void)n_in; (void)out_size; (void)ws_size;
  const float* query = (const float*)d_in[0];
  const float* key_i = (const float*)d_in[1];
  const float* value = (const float*)d_in[2];
  const float* Wq = (const float*)d_in[3];
  const float* bq = (const float*)d_in[4];
  const float* Wk = (const float*)d_in[5];
  const float* bk = (const float*)d_in[6];
  const float* Wv = (const float*)d_in[7];
  const float* bv = (const float*)d_in[8];
  const float* Wo = (const float*)d_in[9];
  const float* bo = (const float*)d_in[10];
  float* out = (float*)d_out;

  char* ws = (char*)d_ws;
  const size_t MB = 1ull << 20;
  uint16_t* xq  = (uint16_t*)(ws + 0 * MB);    // 8 MB each (4096x1024 bf16)
  uint16_t* xk  = (uint16_t*)(ws + 8 * MB);
  uint16_t* xv  = (uint16_t*)(ws + 16 * MB);
  uint16_t* wqb = (uint16_t*)(ws + 24 * MB);   // 2 MB each (1024x1024 bf16)
  uint16_t* wkb = (uint16_t*)(ws + 26 * MB);
  uint16_t* wvb = (uint16_t*)(ws + 28 * MB);
  uint16_t* wob = (uint16_t*)(ws + 30 * MB);
  uint16_t* Qp  = (uint16_t*)(ws + 32 * MB);   // [s][dm], Q pre-scaled
  uint16_t* Kp  = (uint16_t*)(ws + 40 * MB);   // [s][dm]
  uint16_t* VTp = (uint16_t*)(ws + 48 * MB);   // [b,h,d,s]
  uint16_t* AO  = (uint16_t*)(ws + 56 * MB);   // [s][dm], ends at 64 MB

  const int n4x = (MTOT * DM) / 4;
  const int n4w = (DM * DM) / 4;
  CvtArgs ca;
  ca.src[0] = query; ca.dst[0] = xq;
  ca.src[1] = key_i; ca.dst[1] = xk;
  ca.src[2] = value; ca.dst[2] = xv;
  ca.src[3] = Wq;    ca.dst[3] = wqb;
  ca.src[4] = Wk;    ca.dst[4] = wkb;
  ca.src[5] = Wv;    ca.dst[5] = wvb;
  ca.src[6] = Wo;    ca.dst[6] = wob;
  int acc = 0;
  for (int j = 0; j < 7; ++j) { acc += (j < 3) ? n4x : n4w; ca.end4[j] = acc; }
  const int blk = 256;
  cvt_all_kernel<<<(acc + blk - 1) / blk, blk, 0, stream>>>(ca);

  dim3 gg(MTOT / 128, DM / 128);  // 32 x 8
  gemm_bt_128<1><<<gg, 256, 0, stream>>>(xq, wqb, bq, Qp, MTOT, DM, DM);  // Q*QSCALE
  gemm_bt_128<0><<<gg, 256, 0, stream>>>(xk, wkb, bk, Kp, MTOT, DM, DM);
  gemm_bt_128<2><<<gg, 256, 0, stream>>>(xv, wvb, bv, VTp, MTOT, DM, DM); // V^T

  dim3 ga(SEQLEN / 64, NHEAD, NBATCH);  // 32 x 16 x 2
  attn_fwd_kernel<<<ga, 256, 0, stream>>>(Qp, Kp, VTp, AO);

  gemm_bt_128<3><<<gg, 256, 0, stream>>>(AO, wob, bo, out, MTOT, DM, DM);
}

// Round 4
// 163.933 us; speedup vs baseline: 1.7083x; 1.2078x over previous
//
#include <hip/hip_runtime.h>
#include <cstdint>
#include <cstddef>

#define DM 1024
#define NHEAD 16
#define DKH 64
#define SEQLEN 2048
#define NBATCH 2
#define MTOT (NBATCH * SEQLEN)  // 4096

typedef __attribute__((ext_vector_type(8))) short bf16x8;
typedef __attribute__((ext_vector_type(4))) float f32x4;
typedef __attribute__((ext_vector_type(16))) float f32x16;
typedef __attribute__((ext_vector_type(2))) unsigned int u32x2;

// (1/sqrt(Dk)) * log2(e): folded into Q projection; attn softmax uses exp2.
#define QSCALE 0.18033688011112042f

__device__ __forceinline__ uint16_t f2bf(float f) {
  uint32_t x = __float_as_uint(f);
  uint32_t r = x + 0x7FFFu + ((x >> 16) & 1u);  // RNE; inputs finite
  return (uint16_t)(r >> 16);
}

__device__ __forceinline__ uint32_t cvtpk(float a, float b) {
  uint32_t r;
  asm("v_cvt_pk_bf16_f32 %0, %1, %2" : "=v"(r) : "v"(a), "v"(b));
  return r;
}

__device__ __forceinline__ void gload_lds16(const void* g, void* l) {
  __builtin_amdgcn_global_load_lds(
      (const __attribute__((address_space(1))) void*)g,
      (__attribute__((address_space(3))) void*)l, 16, 0, 0);
}

// Swizzle: 16B-slot XOR so 32-row column reads spread over all 8 slots.
__device__ __forceinline__ int fsw(int r) { return ((r + (r >> 3)) & 7) << 4; }

// ---- fused fp32 -> bf16 convert over 7 regions in one launch ----
struct CvtArgs {
  const float* src[7];
  uint16_t* dst[7];
  int end4[7];  // cumulative float4 counts
};

__global__ void cvt_all_kernel(CvtArgs a) {
  int i = blockIdx.x * blockDim.x + threadIdx.x;
  int r = 0;
#pragma unroll
  for (int j = 0; j < 7; ++j)
    if (i >= a.end4[j]) r = j + 1;
  if (r >= 7) return;
  int local = i - (r == 0 ? 0 : a.end4[r - 1]);
  float4 v = reinterpret_cast<const float4*>(a.src[r])[local];
  uint64_t p = (uint64_t)f2bf(v.x) | ((uint64_t)f2bf(v.y) << 16) |
               ((uint64_t)f2bf(v.z) << 32) | ((uint64_t)f2bf(v.w) << 48);
  reinterpret_cast<uint64_t*>(a.dst[r])[local] = p;
}

// ---- fused QKV projection GEMM ----
// grid (M/128, 24): blockIdx.y>>3 selects projection (0=Q,1=K,2=V).
// C = A @ W^T + b; Q scaled by QSCALE; V written transposed to [b,h,d,s].
__global__ __launch_bounds__(256)
void gemm_qkv(const uint16_t* __restrict__ xq, const uint16_t* __restrict__ xk,
              const uint16_t* __restrict__ xv, const uint16_t* __restrict__ wqkv,
              const float* __restrict__ bqp, const float* __restrict__ bkp,
              const float* __restrict__ bvp, uint16_t* __restrict__ Qp,
              uint16_t* __restrict__ Kp, uint16_t* __restrict__ VTp) {
  __shared__ uint16_t smem[2 * 128 * 64];  // 32 KiB
  const int tid = threadIdx.x;
  const int wave = tid >> 6, lane = tid & 63;
  const int l15 = lane & 15, l4 = lane >> 4;
  const int proj = blockIdx.y >> 3;
  const int brow = blockIdx.x * 128, bcol = (blockIdx.y & 7) * 128;
  const int wr = (wave >> 1) * 64, wc = (wave & 1) * 64;
  const uint16_t* A = proj == 0 ? xq : proj == 1 ? xk : xv;
  const uint16_t* Bt = wqkv + (size_t)proj * DM * DM;
  const float* bias = proj == 0 ? bqp : proj == 1 ? bkp : bvp;

  const f32x4 fzero = {0.f, 0.f, 0.f, 0.f};
  f32x4 acc[4][4];
#pragma unroll
  for (int m = 0; m < 4; ++m)
#pragma unroll
    for (int n = 0; n < 4; ++n) acc[m][n] = fzero;

  for (int k0 = 0; k0 < DM; k0 += 64) {
#pragma unroll
    for (int t = 0; t < 8; ++t) {
      const int o = t * 4096 + wave * 1024 + lane * 16;
      const uint16_t* g;
      if (t < 4) {
        const int row = o >> 7, kk = (o & 127) >> 1;
        g = A + (size_t)(brow + row) * DM + (k0 + kk);
      } else {
        const int o2 = o - 16384;
        const int row = o2 >> 7, kk = (o2 & 127) >> 1;
        g = Bt + (size_t)(bcol + row) * DM + (k0 + kk);
      }
      gload_lds16(g, (char*)smem + t * 4096 + wave * 1024);
    }
    __syncthreads();
    const uint16_t* At = smem;
    const uint16_t* Bs = smem + 128 * 64;
#pragma unroll
    for (int ks = 0; ks < 2; ++ks) {
      bf16x8 a[4], b[4];
#pragma unroll
      for (int m = 0; m < 4; ++m)
        a[m] = *(const bf16x8*)(At + (wr + m * 16 + l15) * 64 + ks * 32 + l4 * 8);
#pragma unroll
      for (int n = 0; n < 4; ++n)
        b[n] = *(const bf16x8*)(Bs + (wc + n * 16 + l15) * 64 + ks * 32 + l4 * 8);
#pragma unroll
      for (int m = 0; m < 4; ++m)
#pragma unroll
        for (int n = 0; n < 4; ++n)
          acc[m][n] = __builtin_amdgcn_mfma_f32_16x16x32_bf16(a[m], b[n], acc[m][n], 0, 0, 0);
    }
    __syncthreads();
  }

  const float scale = proj == 0 ? QSCALE : 1.0f;
  uint16_t* dstQK = proj == 0 ? Qp : Kp;
#pragma unroll
  for (int m = 0; m < 4; ++m) {
#pragma unroll
    for (int n = 0; n < 4; ++n) {
      const int gcol = bcol + wc + n * 16 + l15;
      const float bv = bias[gcol];
      if (proj == 2) {
        // V^T: element (s=grow, col=gcol) -> VT[(b*NHEAD+h)*DKH + d][s].
        const int grow0 = brow + wr + m * 16 + l4 * 4;
        const int b_ = grow0 >> 11, s_ = grow0 & 2047;
        const int h_ = gcol >> 6, d_ = gcol & 63;
        uint16_t* dst = VTp + ((size_t)((b_ * NHEAD + h_) * DKH + d_)) * SEQLEN + s_;
        uint64_t pk = (uint64_t)f2bf(acc[m][n][0] + bv) |
                      ((uint64_t)f2bf(acc[m][n][1] + bv) << 16) |
                      ((uint64_t)f2bf(acc[m][n][2] + bv) << 32) |
                      ((uint64_t)f2bf(acc[m][n][3] + bv) << 48);
        *(uint64_t*)dst = pk;
      } else {
#pragma unroll
        for (int r = 0; r < 4; ++r) {
          const int grow = brow + wr + m * 16 + l4 * 4 + r;
          dstQK[(size_t)grow * DM + gcol] = f2bf((acc[m][n][r] + bv) * scale);
        }
      }
    }
  }
}

// ---- output projection GEMM (f32 out) ----
__global__ __launch_bounds__(256)
void gemm_out(const uint16_t* __restrict__ A, const uint16_t* __restrict__ Bt,
              const float* __restrict__ bias, float* __restrict__ C) {
  __shared__ uint16_t smem[2 * 128 * 64];
  const int tid = threadIdx.x;
  const int wave = tid >> 6, lane = tid & 63;
  const int l15 = lane & 15, l4 = lane >> 4;
  const int brow = blockIdx.x * 128, bcol = blockIdx.y * 128;
  const int wr = (wave >> 1) * 64, wc = (wave & 1) * 64;

  const f32x4 fzero = {0.f, 0.f, 0.f, 0.f};
  f32x4 acc[4][4];
#pragma unroll
  for (int m = 0; m < 4; ++m)
#pragma unroll
    for (int n = 0; n < 4; ++n) acc[m][n] = fzero;

  for (int k0 = 0; k0 < DM; k0 += 64) {
#pragma unroll
    for (int t = 0; t < 8; ++t) {
      const int o = t * 4096 + wave * 1024 + lane * 16;
      const uint16_t* g;
      if (t < 4) {
        const int row = o >> 7, kk = (o & 127) >> 1;
        g = A + (size_t)(brow + row) * DM + (k0 + kk);
      } else {
        const int o2 = o - 16384;
        const int row = o2 >> 7, kk = (o2 & 127) >> 1;
        g = Bt + (size_t)(bcol + row) * DM + (k0 + kk);
      }
      gload_lds16(g, (char*)smem + t * 4096 + wave * 1024);
    }
    __syncthreads();
    const uint16_t* At = smem;
    const uint16_t* Bs = smem + 128 * 64;
#pragma unroll
    for (int ks = 0; ks < 2; ++ks) {
      bf16x8 a[4], b[4];
#pragma unroll
      for (int m = 0; m < 4; ++m)
        a[m] = *(const bf16x8*)(At + (wr + m * 16 + l15) * 64 + ks * 32 + l4 * 8);
#pragma unroll
      for (int n = 0; n < 4; ++n)
        b[n] = *(const bf16x8*)(Bs + (wc + n * 16 + l15) * 64 + ks * 32 + l4 * 8);
#pragma unroll
      for (int m = 0; m < 4; ++m)
#pragma unroll
        for (int n = 0; n < 4; ++n)
          acc[m][n] = __builtin_amdgcn_mfma_f32_16x16x32_bf16(a[m], b[n], acc[m][n], 0, 0, 0);
    }
    __syncthreads();
  }

#pragma unroll
  for (int m = 0; m < 4; ++m) {
#pragma unroll
    for (int n = 0; n < 4; ++n) {
      const int gcol = bcol + wc + n * 16 + l15;
      const float bv = bias[gcol];
#pragma unroll
      for (int r = 0; r < 4; ++r) {
        const int grow = brow + wr + m * 16 + l4 * 4 + r;
        C[(size_t)grow * DM + gcol] = acc[m][n][r] + bv;
      }
    }
  }
}

// ---- flash attention, 32x32 MFMA, in-register P ----
// Block = (b, h, 128 q-rows); 4 waves x 32 q-rows. KV tile = 64.
// Swapped QK^T: mfma(K, Q) -> S^T: lane holds S[k][q=lane&31] for
// k = 32n + (reg&3) + 8*(reg>>2) + 4*(lane>>5). Softmax state per-lane
// (q fixed per lane; lanes l and l+32 share q, combined via shfl_xor 32).
// P -> PV B-fragments fully in-register via cvt_pk + permlane32_swap.
// K [k][d] and V^T [d][k] double-buffered in LDS, staged by global_load_lds
// with pre-swizzled source (slot ^= fsw(row); LDS dest linear).
__device__ __forceinline__ void stage_kv(const uint16_t* __restrict__ Kg,
                                         const uint16_t* __restrict__ Vg,
                                         char* buf, int wave, int lane) {
#pragma unroll
  for (int i = 0; i < 2; ++i) {
    const int base = i * 4096 + wave * 1024;
    const int row = i * 32 + wave * 8 + (lane >> 3);
    const int esw = (((lane & 7) << 4) ^ fsw(row)) >> 1;
    gload_lds16(Kg + (size_t)row * DM + esw, buf + base);
    gload_lds16(Vg + (size_t)row * SEQLEN + esw, buf + 8192 + base);
  }
}

__global__ __launch_bounds__(256)
void attn_fwd_kernel(const uint16_t* __restrict__ Qp, const uint16_t* __restrict__ Kp,
                     const uint16_t* __restrict__ VTp, uint16_t* __restrict__ Op) {
  __shared__ __align__(16) char lds[32768];  // 2 bufs x (K 8KB | V^T 8KB)
  const int tid = threadIdx.x;
  const int wave = tid >> 6, lane = tid & 63;
  const int l31 = lane & 31, hi = lane >> 5;
  const int bb = blockIdx.z, h = blockIdx.y;
  const int q0 = blockIdx.x * 128;

  // Q (pre-scaled) in registers: qf[ds] = Q[qrow][ds*16 + hi*8 .. +8].
  const int qrow = q0 + wave * 32 + l31;
  const uint16_t* qb = Qp + ((size_t)(bb * SEQLEN + qrow)) * DM + h * DKH;
  bf16x8 qf[4];
#pragma unroll
  for (int ds = 0; ds < 4; ++ds)
    qf[ds] = *(const bf16x8*)(qb + ds * 16 + hi * 8);

  f32x16 oacc[2];
#pragma unroll
  for (int m = 0; m < 2; ++m)
#pragma unroll
    for (int r = 0; r < 16; ++r) oacc[m][r] = 0.f;
  float mrow = -1e30f, lrow = 0.f;

  const uint16_t* Kg = Kp + ((size_t)(bb * SEQLEN)) * DM + h * DKH;
  const uint16_t* Vg = VTp + ((size_t)((bb * NHEAD + h) * DKH)) * SEQLEN;

  stage_kv(Kg, Vg, lds, wave, lane);  // tile 0 -> buf 0

  const int NT = SEQLEN / 64;
  for (int t = 0; t < NT; ++t) {
    __syncthreads();  // tile t resident (vmcnt drained); buf t+1 free
    if (t + 1 < NT)
      stage_kv(Kg + (size_t)(t + 1) * 64 * DM, Vg + (t + 1) * 64,
               lds + ((t + 1) & 1) * 16384, wave, lane);
    const char* kb = lds + (t & 1) * 16384;
    const char* vb = kb + 8192;

    // S^T = K Q^T via 32x32x16 (8 MFMA).
    f32x16 sacc[2];
#pragma unroll
    for (int n = 0; n < 2; ++n)
#pragma unroll
      for (int r = 0; r < 16; ++r) sacc[n][r] = 0.f;
    __builtin_amdgcn_s_setprio(1);
#pragma unroll
    for (int n = 0; n < 2; ++n) {
      const int kr = 32 * n + l31;
      const char* krow = kb + kr * 128;
      const int f = fsw(kr);
#pragma unroll
      for (int ds = 0; ds < 4; ++ds) {
        const bf16x8 kf = *(const bf16x8*)(krow + ((ds * 32 + hi * 16) ^ f));
        sacc[n] = __builtin_amdgcn_mfma_f32_32x32x16_bf16(kf, qf[ds], sacc[n], 0, 0, 0);
      }
    }
    __builtin_amdgcn_s_setprio(0);

    // Online softmax (log2 domain), per-lane q. One shfl per reduce.
    float mx = sacc[0][0];
#pragma unroll
    for (int n = 0; n < 2; ++n)
#pragma unroll
      for (int r = 0; r < 16; ++r) mx = fmaxf(mx, sacc[n][r]);
    mx = fmaxf(mx, __shfl_xor(mx, 32, 64));
    float mnew = mrow, scl = 1.f;
    if (__any(mx > mrow + 8.f)) {  // defer-max THR=8 (P bounded by 2^8)
      mnew = fmaxf(mrow, mx);
      scl = exp2f(mrow - mnew);
#pragma unroll
      for (int m = 0; m < 2; ++m)
#pragma unroll
        for (int r = 0; r < 16; ++r) oacc[m][r] *= scl;
    }

    float sum = 0.f;
#pragma unroll
    for (int n = 0; n < 2; ++n) {
      float pv[16];
#pragma unroll
      for (int r = 0; r < 16; ++r) {
        pv[r] = exp2f(sacc[n][r] - mnew);
        sum += pv[r];
      }
      // In-register P->bf16 fragments (T12): self holds k quads {0-3,8-11,
      // 16-19,24-27}+4hi; partner (lane^32) the +4 offsets. cvt_pk pairs,
      // permlane32_swap assembles contiguous k 0..15 (ks=0) / 16..31 (ks=1).
      const uint32_t c0 = cvtpk(pv[0], pv[1]),   c1 = cvtpk(pv[2], pv[3]);
      const uint32_t c2 = cvtpk(pv[4], pv[5]),   c3 = cvtpk(pv[6], pv[7]);
      const uint32_t c4 = cvtpk(pv[8], pv[9]),   c5 = cvtpk(pv[10], pv[11]);
      const uint32_t c6 = cvtpk(pv[12], pv[13]), c7 = cvtpk(pv[14], pv[15]);
      const u32x2 r02 = __builtin_amdgcn_permlane32_swap(c0, c2, false, false);
      const u32x2 r13 = __builtin_amdgcn_permlane32_swap(c1, c3, false, false);
      const u32x2 r46 = __builtin_amdgcn_permlane32_swap(c4, c6, false, false);
      const u32x2 r57 = __builtin_amdgcn_permlane32_swap(c5, c7, false, false);
      union { uint32_t w[4]; bf16x8 v; } f0, f1;
      f0.w[0] = r02.x; f0.w[1] = r13.x; f0.w[2] = r02.y; f0.w[3] = r13.y;
      f1.w[0] = r46.x; f1.w[1] = r57.x; f1.w[2] = r46.y; f1.w[3] = r57.y;

      // O^T += V^T P^T  (4 MFMA per k-block).
      __builtin_amdgcn_s_setprio(1);
#pragma unroll
      for (int m = 0; m < 2; ++m) {
        const int vr = 32 * m + l31;
        const char* vrow = vb + vr * 128;
        const int f = fsw(vr);
        const bf16x8 v0 = *(const bf16x8*)(vrow + ((n * 64 + hi * 16) ^ f));
        const bf16x8 v1 = *(const bf16x8*)(vrow + ((n * 64 + 32 + hi * 16) ^ f));
        oacc[m] = __builtin_amdgcn_mfma_f32_32x32x16_bf16(v0, f0.v, oacc[m], 0, 0, 0);
        oacc[m] = __builtin_amdgcn_mfma_f32_32x32x16_bf16(v1, f1.v, oacc[m], 0, 0, 0);
      }
      __builtin_amdgcn_s_setprio(0);
    }
    sum += __shfl_xor(sum, 32, 64);
    lrow = lrow * scl + sum;
    mrow = mnew;
  }

  // Normalize + store. oacc[m][r] = O^T[d][q=l31], d = 32m+(r&3)+8(r>>2)+4hi.
  const float il = 1.0f / lrow;
  uint16_t* ob = Op + ((size_t)(bb * SEQLEN + qrow)) * DM + h * DKH;
#pragma unroll
  for (int m = 0; m < 2; ++m)
#pragma unroll
    for (int rq = 0; rq < 4; ++rq) {
      const uint32_t w0 = cvtpk(oacc[m][4 * rq + 0] * il, oacc[m][4 * rq + 1] * il);
      const uint32_t w1 = cvtpk(oacc[m][4 * rq + 2] * il, oacc[m][4 * rq + 3] * il);
      *(uint64_t*)(ob + 32 * m + 8 * rq + 4 * hi) =
          (uint64_t)w0 | ((uint64_t)w1 << 32);
    }
}

extern "C" void kernel_launch(void* const* d_in, const int* in_sizes, int n_in,
                              void* d_out, int out_size, void* d_ws, size_t ws_size,
                              hipStream_t stream) {
  (void)in_sizes; (void)n_in; (void)out_size; (void)ws_size;
  const float* query = (const float*)d_in[0];
  const float* key_i = (const float*)d_in[1];
  const float* value = (const float*)d_in[2];
  const float* Wq = (const float*)d_in[3];
  const float* bq = (const float*)d_in[4];
  const float* Wk = (const float*)d_in[5];
  const float* bk = (const float*)d_in[6];
  const float* Wv = (const float*)d_in[7];
  const float* bv = (const float*)d_in[8];
  const float* Wo = (const float*)d_in[9];
  const float* bo = (const float*)d_in[10];
  float* out = (float*)d_out;

  char* ws = (char*)d_ws;
  const size_t MB = 1ull << 20;
  uint16_t* xq  = (uint16_t*)(ws + 0 * MB);    // 8 MB each (4096x1024 bf16)
  uint16_t* xk  = (uint16_t*)(ws + 8 * MB);
  uint16_t* xv  = (uint16_t*)(ws + 16 * MB);
  uint16_t* wqkv = (uint16_t*)(ws + 24 * MB);  // 3 x 2 MB contiguous (q,k,v)
  uint16_t* wob = (uint16_t*)(ws + 30 * MB);
  uint16_t* Qp  = (uint16_t*)(ws + 32 * MB);   // [s][dm], Q pre-scaled
  uint16_t* Kp  = (uint16_t*)(ws + 40 * MB);   // [s][dm]
  uint16_t* VTp = (uint16_t*)(ws + 48 * MB);   // [b,h,d,s]
  uint16_t* AO  = (uint16_t*)(ws + 56 * MB);   // [s][dm], ends at 64 MB

  const int n4x = (MTOT * DM) / 4;
  const int n4w = (DM * DM) / 4;
  CvtArgs ca;
  ca.src[0] = query; ca.dst[0] = xq;
  ca.src[1] = key_i; ca.dst[1] = xk;
  ca.src[2] = value; ca.dst[2] = xv;
  ca.src[3] = Wq;    ca.dst[3] = wqkv;
  ca.src[4] = Wk;    ca.dst[4] = wqkv + DM * DM;
  ca.src[5] = Wv;    ca.dst[5] = wqkv + 2 * DM * DM;
  ca.src[6] = Wo;    ca.dst[6] = wob;
  int acc = 0;
  for (int j = 0; j < 7; ++j) { acc += (j < 3) ? n4x : n4w; ca.end4[j] = acc; }
  const int blk = 256;
  cvt_all_kernel<<<(acc + blk - 1) / blk, blk, 0, stream>>>(ca);

  dim3 gq(MTOT / 128, 24);  // 32 x 24 = 768 blocks, 3 projections fused
  gemm_qkv<<<gq, 256, 0, stream>>>(xq, xk, xv, wqkv, bq, bk, bv, Qp, Kp, VTp);

  dim3 ga(SEQLEN / 128, NHEAD, NBATCH);  // 16 x 16 x 2 = 512 blocks
  attn_fwd_kernel<<<ga, 256, 0, stream>>>(Qp, Kp, VTp, AO);

  dim3 gg(MTOT / 128, DM / 128);  // 32 x 8
  gemm_out<<<gg, 256, 0, stream>>>(AO, wob, bo, out);
}

// Round 5
// 153.746 us; speedup vs baseline: 1.8215x; 1.0663x over previous
//
#include <hip/hip_runtime.h>
#include <cstdint>
#include <cstddef>

#define DM 1024
#define NHEAD 16
#define DKH 64
#define SEQLEN 2048
#define NBATCH 2
#define MTOT (NBATCH * SEQLEN)  // 4096

typedef __attribute__((ext_vector_type(8))) short bf16x8;
typedef __attribute__((ext_vector_type(4))) float f32x4;
typedef __attribute__((ext_vector_type(16))) float f32x16;
typedef __attribute__((ext_vector_type(2))) unsigned int u32x2;

// (1/sqrt(Dk)) * log2(e): folded into Q projection; attn softmax uses exp2.
#define QSCALE 0.18033688011112042f

__device__ __forceinline__ uint16_t f2bf(float f) {
  uint32_t x = __float_as_uint(f);
  uint32_t r = x + 0x7FFFu + ((x >> 16) & 1u);  // RNE; inputs finite
  return (uint16_t)(r >> 16);
}

__device__ __forceinline__ uint32_t cvtpk(float a, float b) {
  uint32_t r;
  asm("v_cvt_pk_bf16_f32 %0, %1, %2" : "=v"(r) : "v"(a), "v"(b));
  return r;
}

__device__ __forceinline__ float exp2_fast(float x) {
  float r;
  asm("v_exp_f32 %0, %1" : "=v"(r) : "v"(x));
  return r;
}

__device__ __forceinline__ float max3f(float a, float b, float c) {
  float r;
  asm("v_max3_f32 %0, %1, %2, %3" : "=v"(r) : "v"(a), "v"(b), "v"(c));
  return r;
}

__device__ __forceinline__ void gload_lds16(const void* g, void* l) {
  __builtin_amdgcn_global_load_lds(
      (const __attribute__((address_space(1))) void*)g,
      (__attribute__((address_space(3))) void*)l, 16, 0, 0);
}

// Swizzle: 16B-slot XOR so 32-row column reads spread over all 8 slots.
__device__ __forceinline__ int fsw(int r) { return ((r + (r >> 3)) & 7) << 4; }

// ---- fused fp32 -> bf16 convert over 7 regions in one launch ----
struct CvtArgs {
  const float* src[7];
  uint16_t* dst[7];
  int end4[7];  // cumulative float4 counts
};

__global__ void cvt_all_kernel(CvtArgs a) {
  int i = blockIdx.x * blockDim.x + threadIdx.x;
  int r = 0;
#pragma unroll
  for (int j = 0; j < 7; ++j)
    if (i >= a.end4[j]) r = j + 1;
  if (r >= 7) return;
  int local = i - (r == 0 ? 0 : a.end4[r - 1]);
  float4 v = reinterpret_cast<const float4*>(a.src[r])[local];
  uint64_t p = (uint64_t)f2bf(v.x) | ((uint64_t)f2bf(v.y) << 16) |
               ((uint64_t)f2bf(v.z) << 32) | ((uint64_t)f2bf(v.w) << 48);
  reinterpret_cast<uint64_t*>(a.dst[r])[local] = p;
}

// ---- fused QKV projection GEMM ----
// grid (M/128, 24): blockIdx.y>>3 selects projection (0=Q,1=K,2=V).
// C = A @ W^T + b; Q scaled by QSCALE; V written transposed to [b,h,d,s].
__global__ __launch_bounds__(256)
void gemm_qkv(const uint16_t* __restrict__ xq, const uint16_t* __restrict__ xk,
              const uint16_t* __restrict__ xv, const uint16_t* __restrict__ wqkv,
              const float* __restrict__ bqp, const float* __restrict__ bkp,
              const float* __restrict__ bvp, uint16_t* __restrict__ Qp,
              uint16_t* __restrict__ Kp, uint16_t* __restrict__ VTp) {
  __shared__ uint16_t smem[2 * 128 * 64];  // 32 KiB
  const int tid = threadIdx.x;
  const int wave = tid >> 6, lane = tid & 63;
  const int l15 = lane & 15, l4 = lane >> 4;
  const int proj = blockIdx.y >> 3;
  const int brow = blockIdx.x * 128, bcol = (blockIdx.y & 7) * 128;
  const int wr = (wave >> 1) * 64, wc = (wave & 1) * 64;
  const uint16_t* A = proj == 0 ? xq : proj == 1 ? xk : xv;
  const uint16_t* Bt = wqkv + (size_t)proj * DM * DM;
  const float* bias = proj == 0 ? bqp : proj == 1 ? bkp : bvp;

  const f32x4 fzero = {0.f, 0.f, 0.f, 0.f};
  f32x4 acc[4][4];
#pragma unroll
  for (int m = 0; m < 4; ++m)
#pragma unroll
    for (int n = 0; n < 4; ++n) acc[m][n] = fzero;

  for (int k0 = 0; k0 < DM; k0 += 64) {
#pragma unroll
    for (int t = 0; t < 8; ++t) {
      const int o = t * 4096 + wave * 1024 + lane * 16;
      const uint16_t* g;
      if (t < 4) {
        const int row = o >> 7, kk = (o & 127) >> 1;
        g = A + (size_t)(brow + row) * DM + (k0 + kk);
      } else {
        const int o2 = o - 16384;
        const int row = o2 >> 7, kk = (o2 & 127) >> 1;
        g = Bt + (size_t)(bcol + row) * DM + (k0 + kk);
      }
      gload_lds16(g, (char*)smem + t * 4096 + wave * 1024);
    }
    __syncthreads();
    const uint16_t* At = smem;
    const uint16_t* Bs = smem + 128 * 64;
#pragma unroll
    for (int ks = 0; ks < 2; ++ks) {
      bf16x8 a[4], b[4];
#pragma unroll
      for (int m = 0; m < 4; ++m)
        a[m] = *(const bf16x8*)(At + (wr + m * 16 + l15) * 64 + ks * 32 + l4 * 8);
#pragma unroll
      for (int n = 0; n < 4; ++n)
        b[n] = *(const bf16x8*)(Bs + (wc + n * 16 + l15) * 64 + ks * 32 + l4 * 8);
#pragma unroll
      for (int m = 0; m < 4; ++m)
#pragma unroll
        for (int n = 0; n < 4; ++n)
          acc[m][n] = __builtin_amdgcn_mfma_f32_16x16x32_bf16(a[m], b[n], acc[m][n], 0, 0, 0);
    }
    __syncthreads();
  }

  const float scale = proj == 0 ? QSCALE : 1.0f;
  uint16_t* dstQK = proj == 0 ? Qp : Kp;
#pragma unroll
  for (int m = 0; m < 4; ++m) {
#pragma unroll
    for (int n = 0; n < 4; ++n) {
      const int gcol = bcol + wc + n * 16 + l15;
      const float bv = bias[gcol];
      if (proj == 2) {
        // V^T: element (s=grow, col=gcol) -> VT[(b*NHEAD+h)*DKH + d][s].
        const int grow0 = brow + wr + m * 16 + l4 * 4;
        const int b_ = grow0 >> 11, s_ = grow0 & 2047;
        const int h_ = gcol >> 6, d_ = gcol & 63;
        uint16_t* dst = VTp + ((size_t)((b_ * NHEAD + h_) * DKH + d_)) * SEQLEN + s_;
        uint64_t pk = (uint64_t)f2bf(acc[m][n][0] + bv) |
                      ((uint64_t)f2bf(acc[m][n][1] + bv) << 16) |
                      ((uint64_t)f2bf(acc[m][n][2] + bv) << 32) |
                      ((uint64_t)f2bf(acc[m][n][3] + bv) << 48);
        *(uint64_t*)dst = pk;
      } else {
#pragma unroll
        for (int r = 0; r < 4; ++r) {
          const int grow = brow + wr + m * 16 + l4 * 4 + r;
          dstQK[(size_t)grow * DM + gcol] = f2bf((acc[m][n][r] + bv) * scale);
        }
      }
    }
  }
}

// ---- output projection GEMM (f32 out) ----
__global__ __launch_bounds__(256)
void gemm_out(const uint16_t* __restrict__ A, const uint16_t* __restrict__ Bt,
              const float* __restrict__ bias, float* __restrict__ C) {
  __shared__ uint16_t smem[2 * 128 * 64];
  const int tid = threadIdx.x;
  const int wave = tid >> 6, lane = tid & 63;
  const int l15 = lane & 15, l4 = lane >> 4;
  const int brow = blockIdx.x * 128, bcol = blockIdx.y * 128;
  const int wr = (wave >> 1) * 64, wc = (wave & 1) * 64;

  const f32x4 fzero = {0.f, 0.f, 0.f, 0.f};
  f32x4 acc[4][4];
#pragma unroll
  for (int m = 0; m < 4; ++m)
#pragma unroll
    for (int n = 0; n < 4; ++n) acc[m][n] = fzero;

  for (int k0 = 0; k0 < DM; k0 += 64) {
#pragma unroll
    for (int t = 0; t < 8; ++t) {
      const int o = t * 4096 + wave * 1024 + lane * 16;
      const uint16_t* g;
      if (t < 4) {
        const int row = o >> 7, kk = (o & 127) >> 1;
        g = A + (size_t)(brow + row) * DM + (k0 + kk);
      } else {
        const int o2 = o - 16384;
        const int row = o2 >> 7, kk = (o2 & 127) >> 1;
        g = Bt + (size_t)(bcol + row) * DM + (k0 + kk);
      }
      gload_lds16(g, (char*)smem + t * 4096 + wave * 1024);
    }
    __syncthreads();
    const uint16_t* At = smem;
    const uint16_t* Bs = smem + 128 * 64;
#pragma unroll
    for (int ks = 0; ks < 2; ++ks) {
      bf16x8 a[4], b[4];
#pragma unroll
      for (int m = 0; m < 4; ++m)
        a[m] = *(const bf16x8*)(At + (wr + m * 16 + l15) * 64 + ks * 32 + l4 * 8);
#pragma unroll
      for (int n = 0; n < 4; ++n)
        b[n] = *(const bf16x8*)(Bs + (wc + n * 16 + l15) * 64 + ks * 32 + l4 * 8);
#pragma unroll
      for (int m = 0; m < 4; ++m)
#pragma unroll
        for (int n = 0; n < 4; ++n)
          acc[m][n] = __builtin_amdgcn_mfma_f32_16x16x32_bf16(a[m], b[n], acc[m][n], 0, 0, 0);
    }
    __syncthreads();
  }

#pragma unroll
  for (int m = 0; m < 4; ++m) {
#pragma unroll
    for (int n = 0; n < 4; ++n) {
      const int gcol = bcol + wc + n * 16 + l15;
      const float bv = bias[gcol];
#pragma unroll
      for (int r = 0; r < 4; ++r) {
        const int grow = brow + wr + m * 16 + l4 * 4 + r;
        C[(size_t)grow * DM + gcol] = acc[m][n][r] + bv;
      }
    }
  }
}

// ---- flash attention, 32x32 MFMA, in-register P, MFMA row-sums ----
// Block = (b, h, 128 q-rows); 4 waves x 32 q-rows. KV tile = 64.
// Swapped QK^T: mfma(K, Q) -> S^T. Softmax per-lane (q = lane&31).
// P -> PV B-fragments in-register via cvt_pk + permlane32_swap (T12).
// Row-sum l via mfma(ones, P_frag, lacc): lacc[0] = sum_k P[k][q] for
// both hi halves (C/D row d=4*hi, col q) -> zero shuffles, VALU-free sum.
__device__ __forceinline__ void stage_kv(const uint16_t* __restrict__ Kg,
                                         const uint16_t* __restrict__ Vg,
                                         char* buf, int wave, int lane) {
#pragma unroll
  for (int i = 0; i < 2; ++i) {
    const int base = i * 4096 + wave * 1024;
    const int row = i * 32 + wave * 8 + (lane >> 3);
    const int esw = (((lane & 7) << 4) ^ fsw(row)) >> 1;
    gload_lds16(Kg + (size_t)row * DM + esw, buf + base);
    gload_lds16(Vg + (size_t)row * SEQLEN + esw, buf + 8192 + base);
  }
}

__global__ __launch_bounds__(256)
void attn_fwd_kernel(const uint16_t* __restrict__ Qp, const uint16_t* __restrict__ Kp,
                     const uint16_t* __restrict__ VTp, uint16_t* __restrict__ Op) {
  __shared__ __align__(16) char lds[32768];  // 2 bufs x (K 8KB | V^T 8KB)
  const int tid = threadIdx.x;
  const int wave = tid >> 6, lane = tid & 63;
  const int l31 = lane & 31, hi = lane >> 5;
  const int bb = blockIdx.z, h = blockIdx.y;
  const int q0 = blockIdx.x * 128;

  // Q (pre-scaled) in registers: qf[ds] = Q[qrow][ds*16 + hi*8 .. +8].
  const int qrow = q0 + wave * 32 + l31;
  const uint16_t* qb = Qp + ((size_t)(bb * SEQLEN + qrow)) * DM + h * DKH;
  bf16x8 qf[4];
#pragma unroll
  for (int ds = 0; ds < 4; ++ds)
    qf[ds] = *(const bf16x8*)(qb + ds * 16 + hi * 8);

  bf16x8 onesf;
#pragma unroll
  for (int j = 0; j < 8; ++j) onesf[j] = (short)0x3F80;  // bf16 1.0

  f32x16 oacc[2], lacc;
#pragma unroll
  for (int m = 0; m < 2; ++m)
#pragma unroll
    for (int r = 0; r < 16; ++r) oacc[m][r] = 0.f;
#pragma unroll
  for (int r = 0; r < 16; ++r) lacc[r] = 0.f;
  float mrow = -1e30f;

  const uint16_t* Kg = Kp + ((size_t)(bb * SEQLEN)) * DM + h * DKH;
  const uint16_t* Vg = VTp + ((size_t)((bb * NHEAD + h) * DKH)) * SEQLEN;

  stage_kv(Kg, Vg, lds, wave, lane);  // tile 0 -> buf 0

  const int NT = SEQLEN / 64;
  for (int t = 0; t < NT; ++t) {
    __syncthreads();  // tile t resident (vmcnt drained); buf t+1 free
    if (t + 1 < NT)
      stage_kv(Kg + (size_t)(t + 1) * 64 * DM, Vg + (t + 1) * 64,
               lds + ((t + 1) & 1) * 16384, wave, lane);
    const char* kb = lds + (t & 1) * 16384;
    const char* vb = kb + 8192;

    // S^T = K Q^T via 32x32x16 (8 MFMA).
    f32x16 sacc[2];
#pragma unroll
    for (int n = 0; n < 2; ++n)
#pragma unroll
      for (int r = 0; r < 16; ++r) sacc[n][r] = 0.f;
    __builtin_amdgcn_s_setprio(1);
#pragma unroll
    for (int n = 0; n < 2; ++n) {
      const int kr = 32 * n + l31;
      const char* krow = kb + kr * 128;
      const int f = fsw(kr);
#pragma unroll
      for (int ds = 0; ds < 4; ++ds) {
        const bf16x8 kf = *(const bf16x8*)(krow + ((ds * 32 + hi * 16) ^ f));
        sacc[n] = __builtin_amdgcn_mfma_f32_32x32x16_bf16(kf, qf[ds], sacc[n], 0, 0, 0);
      }
    }
    __builtin_amdgcn_s_setprio(0);

    // Max-reduce via v_max3 trees (depth ~9), one cross-half shfl.
    float ma = max3f(sacc[0][0], sacc[0][1], sacc[0][2]);
    ma = max3f(ma, sacc[0][3], sacc[0][4]);
    ma = max3f(ma, sacc[0][5], sacc[0][6]);
    ma = max3f(ma, sacc[0][7], sacc[0][8]);
    ma = max3f(ma, sacc[0][9], sacc[0][10]);
    ma = max3f(ma, sacc[0][11], sacc[0][12]);
    ma = max3f(ma, sacc[0][13], sacc[0][14]);
    float mb = max3f(sacc[1][0], sacc[1][1], sacc[1][2]);
    mb = max3f(mb, sacc[1][3], sacc[1][4]);
    mb = max3f(mb, sacc[1][5], sacc[1][6]);
    mb = max3f(mb, sacc[1][7], sacc[1][8]);
    mb = max3f(mb, sacc[1][9], sacc[1][10]);
    mb = max3f(mb, sacc[1][11], sacc[1][12]);
    mb = max3f(mb, sacc[1][13], sacc[1][14]);
    float mx = max3f(fmaxf(ma, sacc[0][15]), mb, sacc[1][15]);
    mx = fmaxf(mx, __shfl_xor(mx, 32, 64));

    float mnew = mrow;
    if (__any(mx > mrow + 8.f)) {  // defer-max THR=8 (P bounded by 2^8)
      mnew = fmaxf(mrow, mx);
      const float scl = exp2_fast(mrow - mnew);
#pragma unroll
      for (int m = 0; m < 2; ++m)
#pragma unroll
        for (int r = 0; r < 16; ++r) oacc[m][r] *= scl;
      lacc[0] *= scl;
    }
    mrow = mnew;

#pragma unroll
    for (int n = 0; n < 2; ++n) {
      float pv[16];
#pragma unroll
      for (int r = 0; r < 16; ++r) pv[r] = exp2_fast(sacc[n][r] - mnew);
      // In-register P->bf16 fragments (T12): cvt_pk pairs + permlane32_swap
      // assemble contiguous k 0..15 (f0) / 16..31 (f1) B-fragments.
      const uint32_t c0 = cvtpk(pv[0], pv[1]),   c1 = cvtpk(pv[2], pv[3]);
      const uint32_t c2 = cvtpk(pv[4], pv[5]),   c3 = cvtpk(pv[6], pv[7]);
      const uint32_t c4 = cvtpk(pv[8], pv[9]),   c5 = cvtpk(pv[10], pv[11]);
      const uint32_t c6 = cvtpk(pv[12], pv[13]), c7 = cvtpk(pv[14], pv[15]);
      const u32x2 r02 = __builtin_amdgcn_permlane32_swap(c0, c2, false, false);
      const u32x2 r13 = __builtin_amdgcn_permlane32_swap(c1, c3, false, false);
      const u32x2 r46 = __builtin_amdgcn_permlane32_swap(c4, c6, false, false);
      const u32x2 r57 = __builtin_amdgcn_permlane32_swap(c5, c7, false, false);
      union { uint32_t w[4]; bf16x8 v; } f0, f1;
      f0.w[0] = r02.x; f0.w[1] = r13.x; f0.w[2] = r02.y; f0.w[3] = r13.y;
      f1.w[0] = r46.x; f1.w[1] = r57.x; f1.w[2] = r46.y; f1.w[3] = r57.y;

      // O^T += V^T P^T; l += 1^T P^T (row-sum on the MFMA pipe).
      __builtin_amdgcn_s_setprio(1);
#pragma unroll
      for (int m = 0; m < 2; ++m) {
        const int vr = 32 * m + l31;
        const char* vrow = vb + vr * 128;
        const int f = fsw(vr);
        const bf16x8 v0 = *(const bf16x8*)(vrow + ((n * 64 + hi * 16) ^ f));
        const bf16x8 v1 = *(const bf16x8*)(vrow + ((n * 64 + 32 + hi * 16) ^ f));
        oacc[m] = __builtin_amdgcn_mfma_f32_32x32x16_bf16(v0, f0.v, oacc[m], 0, 0, 0);
        oacc[m] = __builtin_amdgcn_mfma_f32_32x32x16_bf16(v1, f1.v, oacc[m], 0, 0, 0);
      }
      lacc = __builtin_amdgcn_mfma_f32_32x32x16_bf16(onesf, f0.v, lacc, 0, 0, 0);
      lacc = __builtin_amdgcn_mfma_f32_32x32x16_bf16(onesf, f1.v, lacc, 0, 0, 0);
      __builtin_amdgcn_s_setprio(0);
    }
  }

  // Normalize + store. oacc[m][r] = O^T[d][q=l31], d = 32m+(r&3)+8(r>>2)+4hi.
  const float il = 1.0f / lacc[0];
  uint16_t* ob = Op + ((size_t)(bb * SEQLEN + qrow)) * DM + h * DKH;
#pragma unroll
  for (int m = 0; m < 2; ++m)
#pragma unroll
    for (int rq = 0; rq < 4; ++rq) {
      const uint32_t w0 = cvtpk(oacc[m][4 * rq + 0] * il, oacc[m][4 * rq + 1] * il);
      const uint32_t w1 = cvtpk(oacc[m][4 * rq + 2] * il, oacc[m][4 * rq + 3] * il);
      *(uint64_t*)(ob + 32 * m + 8 * rq + 4 * hi) =
          (uint64_t)w0 | ((uint64_t)w1 << 32);
    }
}

extern "C" void kernel_launch(void* const* d_in, const int* in_sizes, int n_in,
                              void* d_out, int out_size, void* d_ws, size_t ws_size,
                              hipStream_t stream) {
  (void)in_sizes; (void)n_in; (void)out_size; (void)ws_size;
  const float* query = (const float*)d_in[0];
  const float* key_i = (const float*)d_in[1];
  const float* value = (const float*)d_in[2];
  const float* Wq = (const float*)d_in[3];
  const float* bq = (const float*)d_in[4];
  const float* Wk = (const float*)d_in[5];
  const float* bk = (const float*)d_in[6];
  const float* Wv = (const float*)d_in[7];
  const float* bv = (const float*)d_in[8];
  const float* Wo = (const float*)d_in[9];
  const float* bo = (const float*)d_in[10];
  float* out = (float*)d_out;

  char* ws = (char*)d_ws;
  const size_t MB = 1ull << 20;
  uint16_t* xq  = (uint16_t*)(ws + 0 * MB);    // 8 MB each (4096x1024 bf16)
  uint16_t* xk  = (uint16_t*)(ws + 8 * MB);
  uint16_t* xv  = (uint16_t*)(ws + 16 * MB);
  uint16_t* wqkv = (uint16_t*)(ws + 24 * MB);  // 3 x 2 MB contiguous (q,k,v)
  uint16_t* wob = (uint16_t*)(ws + 30 * MB);
  uint16_t* Qp  = (uint16_t*)(ws + 32 * MB);   // [s][dm], Q pre-scaled
  uint16_t* Kp  = (uint16_t*)(ws + 40 * MB);   // [s][dm]
  uint16_t* VTp = (uint16_t*)(ws + 48 * MB);   // [b,h,d,s]
  uint16_t* AO  = (uint16_t*)(ws + 56 * MB);   // [s][dm], ends at 64 MB

  const int n4x = (MTOT * DM) / 4;
  const int n4w = (DM * DM) / 4;
  CvtArgs ca;
  ca.src[0] = query; ca.dst[0] = xq;
  ca.src[1] = key_i; ca.dst[1] = xk;
  ca.src[2] = value; ca.dst[2] = xv;
  ca.src[3] = Wq;    ca.dst[3] = wqkv;
  ca.src[4] = Wk;    ca.dst[4] = wqkv + DM * DM;
  ca.src[5] = Wv;    ca.dst[5] = wqkv + 2 * DM * DM;
  ca.src[6] = Wo;    ca.dst[6] = wob;
  int acc = 0;
  for (int j = 0; j < 7; ++j) { acc += (j < 3) ? n4x : n4w; ca.end4[j] = acc; }
  const int blk = 256;
  cvt_all_kernel<<<(acc + blk - 1) / blk, blk, 0, stream>>>(ca);

  dim3 gq(MTOT / 128, 24);  // 32 x 24 = 768 blocks, 3 projections fused
  gemm_qkv<<<gq, 256, 0, stream>>>(xq, xk, xv, wqkv, bq, bk, bv, Qp, Kp, VTp);

  dim3 ga(SEQLEN / 128, NHEAD, NBATCH);  // 16 x 16 x 2 = 512 blocks
  attn_fwd_kernel<<<ga, 256, 0, stream>>>(Qp, Kp, VTp, AO);

  dim3 gg(MTOT / 128, DM / 128);  // 32 x 8
  gemm_out<<<gg, 256, 0, stream>>>(AO, wob, bo, out);
}

// Round 6
// 131.287 us; speedup vs baseline: 2.1331x; 1.1711x over previous
//
#include <hip/hip_runtime.h>
#include <cstdint>
#include <cstddef>

#define DM 1024
#define NHEAD 16
#define DKH 64
#define SEQLEN 2048
#define NBATCH 2
#define MTOT (NBATCH * SEQLEN)  // 4096

typedef __attribute__((ext_vector_type(8))) short bf16x8;
typedef __attribute__((ext_vector_type(4))) float f32x4;
typedef __attribute__((ext_vector_type(16))) float f32x16;
typedef __attribute__((ext_vector_type(2))) unsigned int u32x2;

// (1/sqrt(Dk)) * log2(e): folded into Q projection; attn softmax uses exp2.
#define QSCALE 0.18033688011112042f

__device__ __forceinline__ uint16_t f2bf(float f) {
  uint32_t x = __float_as_uint(f);
  uint32_t r = x + 0x7FFFu + ((x >> 16) & 1u);  // RNE; inputs finite
  return (uint16_t)(r >> 16);
}

__device__ __forceinline__ uint32_t cvtpk(float a, float b) {
  uint32_t r;
  asm("v_cvt_pk_bf16_f32 %0, %1, %2" : "=v"(r) : "v"(a), "v"(b));
  return r;
}

__device__ __forceinline__ float exp2_fast(float x) {
  float r;
  asm("v_exp_f32 %0, %1" : "=v"(r) : "v"(x));
  return r;
}

__device__ __forceinline__ float max3f(float a, float b, float c) {
  float r;
  asm("v_max3_f32 %0, %1, %2, %3" : "=v"(r) : "v"(a), "v"(b), "v"(c));
  return r;
}

__device__ __forceinline__ void gload_lds16(const void* g, void* l) {
  __builtin_amdgcn_global_load_lds(
      (const __attribute__((address_space(1))) void*)g,
      (__attribute__((address_space(3))) void*)l, 16, 0, 0);
}

// Swizzle: 16B-slot XOR so 32-row column reads spread over all 8 slots.
__device__ __forceinline__ int fsw(int r) { return ((r + (r >> 3)) & 7) << 4; }

// ---- fused fp32 -> bf16 convert over 7 regions in one launch ----
struct CvtArgs {
  const float* src[7];
  uint16_t* dst[7];
  int end4[7];  // cumulative float4 counts
};

__global__ void cvt_all_kernel(CvtArgs a) {
  int i = blockIdx.x * blockDim.x + threadIdx.x;
  int r = 0;
#pragma unroll
  for (int j = 0; j < 7; ++j)
    if (i >= a.end4[j]) r = j + 1;
  if (r >= 7) return;
  int local = i - (r == 0 ? 0 : a.end4[r - 1]);
  float4 v = reinterpret_cast<const float4*>(a.src[r])[local];
  uint64_t p = (uint64_t)f2bf(v.x) | ((uint64_t)f2bf(v.y) << 16) |
               ((uint64_t)f2bf(v.z) << 32) | ((uint64_t)f2bf(v.w) << 48);
  reinterpret_cast<uint64_t*>(a.dst[r])[local] = p;
}

// Stage one 128x64 A-tile + 128x64 B-tile (32 KiB) into LDS buffer `buf`.
// T3-min 2-phase: called for tile t+1 BEFORE computing tile t.
__device__ __forceinline__ void gemm_stage(const uint16_t* __restrict__ A,
                                           const uint16_t* __restrict__ Bt,
                                           int brow, int bcol, int k0,
                                           char* smem, int buf, int wave, int lane) {
#pragma unroll
  for (int t = 0; t < 8; ++t) {
    const int o = t * 4096 + wave * 1024 + lane * 16;
    const uint16_t* g;
    if (t < 4) {
      const int row = o >> 7, kk = (o & 127) >> 1;
      g = A + (size_t)(brow + row) * DM + (k0 + kk);
    } else {
      const int o2 = o - 16384;
      const int row = o2 >> 7, kk = (o2 & 127) >> 1;
      g = Bt + (size_t)(bcol + row) * DM + (k0 + kk);
    }
    gload_lds16(g, smem + buf * 32768 + t * 4096 + wave * 1024);
  }
}

// ---- fused QKV projection GEMM (2-phase double-buffered) ----
// grid (M/128, 24): blockIdx.y>>3 selects projection (0=Q,1=K,2=V).
// C = A @ W^T + b; Q scaled by QSCALE; V written transposed to [b,h,d,s].
__global__ __launch_bounds__(256)
void gemm_qkv(const uint16_t* __restrict__ xq, const uint16_t* __restrict__ xk,
              const uint16_t* __restrict__ xv, const uint16_t* __restrict__ wqkv,
              const float* __restrict__ bqp, const float* __restrict__ bkp,
              const float* __restrict__ bvp, uint16_t* __restrict__ Qp,
              uint16_t* __restrict__ Kp, uint16_t* __restrict__ VTp) {
  __shared__ uint16_t smem[2 * 2 * 128 * 64];  // 64 KiB: 2 bufs x (A|B)
  const int tid = threadIdx.x;
  const int wave = tid >> 6, lane = tid & 63;
  const int l15 = lane & 15, l4 = lane >> 4;
  const int proj = blockIdx.y >> 3;
  const int brow = blockIdx.x * 128, bcol = (blockIdx.y & 7) * 128;
  const int wr = (wave >> 1) * 64, wc = (wave & 1) * 64;
  const uint16_t* A = proj == 0 ? xq : proj == 1 ? xk : xv;
  const uint16_t* Bt = wqkv + (size_t)proj * DM * DM;
  const float* bias = proj == 0 ? bqp : proj == 1 ? bkp : bvp;

  const f32x4 fzero = {0.f, 0.f, 0.f, 0.f};
  f32x4 acc[4][4];
#pragma unroll
  for (int m = 0; m < 4; ++m)
#pragma unroll
    for (int n = 0; n < 4; ++n) acc[m][n] = fzero;

  gemm_stage(A, Bt, brow, bcol, 0, (char*)smem, 0, wave, lane);
  int cur = 0;
  for (int k0 = 0; k0 < DM; k0 += 64) {
    __syncthreads();  // loads for buf[cur] drained; buf[cur^1] free of readers
    if (k0 + 64 < DM)
      gemm_stage(A, Bt, brow, bcol, k0 + 64, (char*)smem, cur ^ 1, wave, lane);
    const uint16_t* At = smem + cur * 16384;
    const uint16_t* Bs = At + 8192;
#pragma unroll
    for (int ks = 0; ks < 2; ++ks) {
      bf16x8 a[4], b[4];
#pragma unroll
      for (int m = 0; m < 4; ++m)
        a[m] = *(const bf16x8*)(At + (wr + m * 16 + l15) * 64 + ks * 32 + l4 * 8);
#pragma unroll
      for (int n = 0; n < 4; ++n)
        b[n] = *(const bf16x8*)(Bs + (wc + n * 16 + l15) * 64 + ks * 32 + l4 * 8);
#pragma unroll
      for (int m = 0; m < 4; ++m)
#pragma unroll
        for (int n = 0; n < 4; ++n)
          acc[m][n] = __builtin_amdgcn_mfma_f32_16x16x32_bf16(a[m], b[n], acc[m][n], 0, 0, 0);
    }
    cur ^= 1;
  }

  const float scale = proj == 0 ? QSCALE : 1.0f;
  uint16_t* dstQK = proj == 0 ? Qp : Kp;
#pragma unroll
  for (int m = 0; m < 4; ++m) {
#pragma unroll
    for (int n = 0; n < 4; ++n) {
      const int gcol = bcol + wc + n * 16 + l15;
      const float bv = bias[gcol];
      if (proj == 2) {
        // V^T: element (s=grow, col=gcol) -> VT[(b*NHEAD+h)*DKH + d][s].
        const int grow0 = brow + wr + m * 16 + l4 * 4;
        const int b_ = grow0 >> 11, s_ = grow0 & 2047;
        const int h_ = gcol >> 6, d_ = gcol & 63;
        uint16_t* dst = VTp + ((size_t)((b_ * NHEAD + h_) * DKH + d_)) * SEQLEN + s_;
        uint64_t pk = (uint64_t)f2bf(acc[m][n][0] + bv) |
                      ((uint64_t)f2bf(acc[m][n][1] + bv) << 16) |
                      ((uint64_t)f2bf(acc[m][n][2] + bv) << 32) |
                      ((uint64_t)f2bf(acc[m][n][3] + bv) << 48);
        *(uint64_t*)dst = pk;
      } else {
#pragma unroll
        for (int r = 0; r < 4; ++r) {
          const int grow = brow + wr + m * 16 + l4 * 4 + r;
          dstQK[(size_t)grow * DM + gcol] = f2bf((acc[m][n][r] + bv) * scale);
        }
      }
    }
  }
}

// ---- output projection GEMM (f32 out, 2-phase double-buffered) ----
__global__ __launch_bounds__(256)
void gemm_out(const uint16_t* __restrict__ A, const uint16_t* __restrict__ Bt,
              const float* __restrict__ bias, float* __restrict__ C) {
  __shared__ uint16_t smem[2 * 2 * 128 * 64];  // 64 KiB
  const int tid = threadIdx.x;
  const int wave = tid >> 6, lane = tid & 63;
  const int l15 = lane & 15, l4 = lane >> 4;
  const int brow = blockIdx.x * 128, bcol = blockIdx.y * 128;
  const int wr = (wave >> 1) * 64, wc = (wave & 1) * 64;

  const f32x4 fzero = {0.f, 0.f, 0.f, 0.f};
  f32x4 acc[4][4];
#pragma unroll
  for (int m = 0; m < 4; ++m)
#pragma unroll
    for (int n = 0; n < 4; ++n) acc[m][n] = fzero;

  gemm_stage(A, Bt, brow, bcol, 0, (char*)smem, 0, wave, lane);
  int cur = 0;
  for (int k0 = 0; k0 < DM; k0 += 64) {
    __syncthreads();
    if (k0 + 64 < DM)
      gemm_stage(A, Bt, brow, bcol, k0 + 64, (char*)smem, cur ^ 1, wave, lane);
    const uint16_t* At = smem + cur * 16384;
    const uint16_t* Bs = At + 8192;
#pragma unroll
    for (int ks = 0; ks < 2; ++ks) {
      bf16x8 a[4], b[4];
#pragma unroll
      for (int m = 0; m < 4; ++m)
        a[m] = *(const bf16x8*)(At + (wr + m * 16 + l15) * 64 + ks * 32 + l4 * 8);
#pragma unroll
      for (int n = 0; n < 4; ++n)
        b[n] = *(const bf16x8*)(Bs + (wc + n * 16 + l15) * 64 + ks * 32 + l4 * 8);
#pragma unroll
      for (int m = 0; m < 4; ++m)
#pragma unroll
        for (int n = 0; n < 4; ++n)
          acc[m][n] = __builtin_amdgcn_mfma_f32_16x16x32_bf16(a[m], b[n], acc[m][n], 0, 0, 0);
    }
    cur ^= 1;
  }

#pragma unroll
  for (int m = 0; m < 4; ++m) {
#pragma unroll
    for (int n = 0; n < 4; ++n) {
      const int gcol = bcol + wc + n * 16 + l15;
      const float bv = bias[gcol];
#pragma unroll
      for (int r = 0; r < 4; ++r) {
        const int grow = brow + wr + m * 16 + l4 * 4 + r;
        C[(size_t)grow * DM + gcol] = acc[m][n][r] + bv;
      }
    }
  }
}

// ---- flash attention, 32x32 MFMA, in-register P, MFMA row-sums ----
// Block = (b, h, 128 q-rows); 4 waves x 32 q-rows. KV tile = 64.
// Swapped QK^T: mfma(K, Q) -> S^T. Softmax per-lane (q = lane&31).
// P -> PV B-fragments in-register via cvt_pk + permlane32_swap (T12).
// Row-sum l via mfma(ones, P_frag, lacc).
__device__ __forceinline__ void stage_kv(const uint16_t* __restrict__ Kg,
                                         const uint16_t* __restrict__ Vg,
                                         char* buf, int wave, int lane) {
#pragma unroll
  for (int i = 0; i < 2; ++i) {
    const int base = i * 4096 + wave * 1024;
    const int row = i * 32 + wave * 8 + (lane >> 3);
    const int esw = (((lane & 7) << 4) ^ fsw(row)) >> 1;
    gload_lds16(Kg + (size_t)row * DM + esw, buf + base);
    gload_lds16(Vg + (size_t)row * SEQLEN + esw, buf + 8192 + base);
  }
}

__global__ __launch_bounds__(256)
void attn_fwd_kernel(const uint16_t* __restrict__ Qp, const uint16_t* __restrict__ Kp,
                     const uint16_t* __restrict__ VTp, uint16_t* __restrict__ Op) {
  __shared__ __align__(16) char lds[32768];  // 2 bufs x (K 8KB | V^T 8KB)
  const int tid = threadIdx.x;
  const int wave = tid >> 6, lane = tid & 63;
  const int l31 = lane & 31, hi = lane >> 5;
  const int bb = blockIdx.z, h = blockIdx.y;
  const int q0 = blockIdx.x * 128;

  // Q (pre-scaled) in registers: qf[ds] = Q[qrow][ds*16 + hi*8 .. +8].
  const int qrow = q0 + wave * 32 + l31;
  const uint16_t* qb = Qp + ((size_t)(bb * SEQLEN + qrow)) * DM + h * DKH;
  bf16x8 qf[4];
#pragma unroll
  for (int ds = 0; ds < 4; ++ds)
    qf[ds] = *(const bf16x8*)(qb + ds * 16 + hi * 8);

  bf16x8 onesf;
#pragma unroll
  for (int j = 0; j < 8; ++j) onesf[j] = (short)0x3F80;  // bf16 1.0

  f32x16 oacc[2], lacc;
#pragma unroll
  for (int m = 0; m < 2; ++m)
#pragma unroll
    for (int r = 0; r < 16; ++r) oacc[m][r] = 0.f;
#pragma unroll
  for (int r = 0; r < 16; ++r) lacc[r] = 0.f;
  float mrow = -1e30f;

  const uint16_t* Kg = Kp + ((size_t)(bb * SEQLEN)) * DM + h * DKH;
  const uint16_t* Vg = VTp + ((size_t)((bb * NHEAD + h) * DKH)) * SEQLEN;

  stage_kv(Kg, Vg, lds, wave, lane);  // tile 0 -> buf 0

  const int NT = SEQLEN / 64;
  for (int t = 0; t < NT; ++t) {
    __syncthreads();  // tile t resident (vmcnt drained); buf t+1 free
    if (t + 1 < NT)
      stage_kv(Kg + (size_t)(t + 1) * 64 * DM, Vg + (t + 1) * 64,
               lds + ((t + 1) & 1) * 16384, wave, lane);
    const char* kb = lds + (t & 1) * 16384;
    const char* vb = kb + 8192;

    // S^T = K Q^T via 32x32x16 (8 MFMA).
    f32x16 sacc[2];
#pragma unroll
    for (int n = 0; n < 2; ++n)
#pragma unroll
      for (int r = 0; r < 16; ++r) sacc[n][r] = 0.f;
    __builtin_amdgcn_s_setprio(1);
#pragma unroll
    for (int n = 0; n < 2; ++n) {
      const int kr = 32 * n + l31;
      const char* krow = kb + kr * 128;
      const int f = fsw(kr);
#pragma unroll
      for (int ds = 0; ds < 4; ++ds) {
        const bf16x8 kf = *(const bf16x8*)(krow + ((ds * 32 + hi * 16) ^ f));
        sacc[n] = __builtin_amdgcn_mfma_f32_32x32x16_bf16(kf, qf[ds], sacc[n], 0, 0, 0);
      }
    }
    __builtin_amdgcn_s_setprio(0);

    // Max-reduce via v_max3 trees (depth ~9), one cross-half shfl.
    float ma = max3f(sacc[0][0], sacc[0][1], sacc[0][2]);
    ma = max3f(ma, sacc[0][3], sacc[0][4]);
    ma = max3f(ma, sacc[0][5], sacc[0][6]);
    ma = max3f(ma, sacc[0][7], sacc[0][8]);
    ma = max3f(ma, sacc[0][9], sacc[0][10]);
    ma = max3f(ma, sacc[0][11], sacc[0][12]);
    ma = max3f(ma, sacc[0][13], sacc[0][14]);
    float mb = max3f(sacc[1][0], sacc[1][1], sacc[1][2]);
    mb = max3f(mb, sacc[1][3], sacc[1][4]);
    mb = max3f(mb, sacc[1][5], sacc[1][6]);
    mb = max3f(mb, sacc[1][7], sacc[1][8]);
    mb = max3f(mb, sacc[1][9], sacc[1][10]);
    mb = max3f(mb, sacc[1][11], sacc[1][12]);
    mb = max3f(mb, sacc[1][13], sacc[1][14]);
    float mx = max3f(fmaxf(ma, sacc[0][15]), mb, sacc[1][15]);
    mx = fmaxf(mx, __shfl_xor(mx, 32, 64));

    float mnew = mrow;
    if (__any(mx > mrow + 8.f)) {  // defer-max THR=8 (P bounded by 2^8)
      mnew = fmaxf(mrow, mx);
      const float scl = exp2_fast(mrow - mnew);
#pragma unroll
      for (int m = 0; m < 2; ++m)
#pragma unroll
        for (int r = 0; r < 16; ++r) oacc[m][r] *= scl;
      lacc[0] *= scl;
    }
    mrow = mnew;

#pragma unroll
    for (int n = 0; n < 2; ++n) {
      float pv[16];
#pragma unroll
      for (int r = 0; r < 16; ++r) pv[r] = exp2_fast(sacc[n][r] - mnew);
      // In-register P->bf16 fragments (T12): cvt_pk pairs + permlane32_swap
      // assemble contiguous k 0..15 (f0) / 16..31 (f1) B-fragments.
      const uint32_t c0 = cvtpk(pv[0], pv[1]),   c1 = cvtpk(pv[2], pv[3]);
      const uint32_t c2 = cvtpk(pv[4], pv[5]),   c3 = cvtpk(pv[6], pv[7]);
      const uint32_t c4 = cvtpk(pv[8], pv[9]),   c5 = cvtpk(pv[10], pv[11]);
      const uint32_t c6 = cvtpk(pv[12], pv[13]), c7 = cvtpk(pv[14], pv[15]);
      const u32x2 r02 = __builtin_amdgcn_permlane32_swap(c0, c2, false, false);
      const u32x2 r13 = __builtin_amdgcn_permlane32_swap(c1, c3, false, false);
      const u32x2 r46 = __builtin_amdgcn_permlane32_swap(c4, c6, false, false);
      const u32x2 r57 = __builtin_amdgcn_permlane32_swap(c5, c7, false, false);
      union { uint32_t w[4]; bf16x8 v; } f0, f1;
      f0.w[0] = r02.x; f0.w[1] = r13.x; f0.w[2] = r02.y; f0.w[3] = r13.y;
      f1.w[0] = r46.x; f1.w[1] = r57.x; f1.w[2] = r46.y; f1.w[3] = r57.y;

      // O^T += V^T P^T; l += 1^T P^T (row-sum on the MFMA pipe).
      __builtin_amdgcn_s_setprio(1);
#pragma unroll
      for (int m = 0; m < 2; ++m) {
        const int vr = 32 * m + l31;
        const char* vrow = vb + vr * 128;
        const int f = fsw(vr);
        const bf16x8 v0 = *(const bf16x8*)(vrow + ((n * 64 + hi * 16) ^ f));
        const bf16x8 v1 = *(const bf16x8*)(vrow + ((n * 64 + 32 + hi * 16) ^ f));
        oacc[m] = __builtin_amdgcn_mfma_f32_32x32x16_bf16(v0, f0.v, oacc[m], 0, 0, 0);
        oacc[m] = __builtin_amdgcn_mfma_f32_32x32x16_bf16(v1, f1.v, oacc[m], 0, 0, 0);
      }
      lacc = __builtin_amdgcn_mfma_f32_32x32x16_bf16(onesf, f0.v, lacc, 0, 0, 0);
      lacc = __builtin_amdgcn_mfma_f32_32x32x16_bf16(onesf, f1.v, lacc, 0, 0, 0);
      __builtin_amdgcn_s_setprio(0);
    }
  }

  // Normalize + store. oacc[m][r] = O^T[d][q=l31], d = 32m+(r&3)+8(r>>2)+4hi.
  const float il = 1.0f / lacc[0];
  uint16_t* ob = Op + ((size_t)(bb * SEQLEN + qrow)) * DM + h * DKH;
#pragma unroll
  for (int m = 0; m < 2; ++m)
#pragma unroll
    for (int rq = 0; rq < 4; ++rq) {
      const uint32_t w0 = cvtpk(oacc[m][4 * rq + 0] * il, oacc[m][4 * rq + 1] * il);
      const uint32_t w1 = cvtpk(oacc[m][4 * rq + 2] * il, oacc[m][4 * rq + 3] * il);
      *(uint64_t*)(ob + 32 * m + 8 * rq + 4 * hi) =
          (uint64_t)w0 | ((uint64_t)w1 << 32);
    }
}

extern "C" void kernel_launch(void* const* d_in, const int* in_sizes, int n_in,
                              void* d_out, int out_size, void* d_ws, size_t ws_size,
                              hipStream_t stream) {
  (void)in_sizes; (void)n_in; (void)out_size; (void)ws_size;
  const float* query = (const float*)d_in[0];
  const float* key_i = (const float*)d_in[1];
  const float* value = (const float*)d_in[2];
  const float* Wq = (const float*)d_in[3];
  const float* bq = (const float*)d_in[4];
  const float* Wk = (const float*)d_in[5];
  const float* bk = (const float*)d_in[6];
  const float* Wv = (const float*)d_in[7];
  const float* bv = (const float*)d_in[8];
  const float* Wo = (const float*)d_in[9];
  const float* bo = (const float*)d_in[10];
  float* out = (float*)d_out;

  char* ws = (char*)d_ws;
  const size_t MB = 1ull << 20;
  uint16_t* xq  = (uint16_t*)(ws + 0 * MB);    // 8 MB each (4096x1024 bf16)
  uint16_t* xk  = (uint16_t*)(ws + 8 * MB);
  uint16_t* xv  = (uint16_t*)(ws + 16 * MB);
  uint16_t* wqkv = (uint16_t*)(ws + 24 * MB);  // 3 x 2 MB contiguous (q,k,v)
  uint16_t* wob = (uint16_t*)(ws + 30 * MB);
  uint16_t* Qp  = (uint16_t*)(ws + 32 * MB);   // [s][dm], Q pre-scaled
  uint16_t* Kp  = (uint16_t*)(ws + 40 * MB);   // [s][dm]
  uint16_t* VTp = (uint16_t*)(ws + 48 * MB);   // [b,h,d,s]
  uint16_t* AO  = (uint16_t*)(ws + 56 * MB);   // [s][dm], ends at 64 MB

  const int n4x = (MTOT * DM) / 4;
  const int n4w = (DM * DM) / 4;
  CvtArgs ca;
  ca.src[0] = query; ca.dst[0] = xq;
  ca.src[1] = key_i; ca.dst[1] = xk;
  ca.src[2] = value; ca.dst[2] = xv;
  ca.src[3] = Wq;    ca.dst[3] = wqkv;
  ca.src[4] = Wk;    ca.dst[4] = wqkv + DM * DM;
  ca.src[5] = Wv;    ca.dst[5] = wqkv + 2 * DM * DM;
  ca.src[6] = Wo;    ca.dst[6] = wob;
  int acc = 0;
  for (int j = 0; j < 7; ++j) { acc += (j < 3) ? n4x : n4w; ca.end4[j] = acc; }
  const int blk = 256;
  cvt_all_kernel<<<(acc + blk - 1) / blk, blk, 0, stream>>>(ca);

  dim3 gq(MTOT / 128, 24);  // 32 x 24 = 768 blocks, 3 projections fused
  gemm_qkv<<<gq, 256, 0, stream>>>(xq, xk, xv, wqkv, bq, bk, bv, Qp, Kp, VTp);

  dim3 ga(SEQLEN / 128, NHEAD, NBATCH);  // 16 x 16 x 2 = 512 blocks
  attn_fwd_kernel<<<ga, 256, 0, stream>>>(Qp, Kp, VTp, AO);

  dim3 gg(MTOT / 128, DM / 128);  // 32 x 8
  gemm_out<<<gg, 256, 0, stream>>>(AO, wob, bo, out);
}